// Round 3
// baseline (484.756 us; speedup 1.0000x reference)
//
#include <hip/hip_runtime.h>
#include <float.h>
#include <stdint.h>

#define NUM_CELLS 2048
#define CELL_DIM  256
#define N_STATES  131072

typedef _Float16 half8 __attribute__((ext_vector_type(8)));
typedef float    f32x4 __attribute__((ext_vector_type(4)));
typedef float    f32x4v __attribute__((ext_vector_type(4)));   // nt-load-able

// Stage-1 (1-pass fp16) sim-difference noise sigma ~6e-3; M1 ~ 17 sigma.
#define M1 0.10f
// Stage-2 (fp16x2 3-pass) noise sigma ~1.5e-5; M2 = 0.0008 ~ 50 sigma.
#define M2 0.0008f
#define CAP1 32768
#define CAP2 4096

// ws layout (bytes). ws_size >= WS_NEEDED confirmed (rounds 2-4 ran this path).
#define WS_C1 0
#define WS_C2 4
#define WS_L1 1024
#define WS_L2 (WS_L1 + 4 * CAP1)                    // 132096
#define WS_PH 262144
#define WS_PL (WS_PH + 1048576)
// 128 KB slack after pl retained (layout unchanged from verified rounds).
#define WS_NEEDED (WS_PL + 1048576 + 131072)        // 2490368

#define AS1 __attribute__((address_space(1)))
#define AS3 __attribute__((address_space(3)))

// ---------------------------------------------------------------------------
// Prep: p fp32 -> B-fragment-order fp16 hi + (lo*2048) arrays; zero counters.
// Frag order (16x16x32 f16 B): half8 index d = (ct*8 + kf)*64 + l, where
// cell = ct*16 + (l&15), k = kf*32 + (l>>4)*8 + j.
// ---------------------------------------------------------------------------
__global__ void prep_p(const float* __restrict__ p, _Float16* __restrict__ ph,
                       _Float16* __restrict__ pl, int* __restrict__ c1,
                       int* __restrict__ c2) {
    int d = blockIdx.x * 256 + threadIdx.x;   // 65536 dests
    if (d == 0) { *c1 = 0; *c2 = 0; }
    int l = d & 63, kf = (d >> 6) & 7, ct = d >> 9;
    int cell = ct * 16 + (l & 15);
    int k0 = kf * 32 + (l >> 4) * 8;
    const float* s = p + cell * 256 + k0;
    float4 a = *(const float4*)s, b = *(const float4*)(s + 4);
    float v[8] = {a.x, a.y, a.z, a.w, b.x, b.y, b.z, b.w};
    half8 h, lo;
#pragma unroll
    for (int j = 0; j < 8; ++j) {
        _Float16 hi = (_Float16)v[j];
        h[j] = hi;
        lo[j] = (_Float16)((v[j] - (float)hi) * 2048.0f);  // scaled: no fp16 denorms
    }
    *(half8*)(ph + (size_t)d * 8) = h;
    *(half8*)(pl + (size_t)d * 8) = lo;
}

// ---------------------------------------------------------------------------
// Kernel A: 1-pass fp16 MFMA GEMM, counted-vmcnt pipelined B-stream (T3+T4).
// Block = 128 rows; 512 thr = 8 waves (wr 0..1 row half x wc 0..3 col group).
// A-frags (64 rows x K=256) in 128 VGPRs. B staged block-cooperatively into a
// 4 x 32 KB LDS ring via global_load_lds, depth-3 prefetch. Per-tile barrier
// = fused "s_waitcnt vmcnt(8); s_barrier" (single volatile asm): only the
// OLDEST in-flight tile retires; 8 loads (2 tiles) stay in flight ACROSS the
// barrier (never vmcnt(0) in the loop -- the round-1 __syncthreads drain was
// ~56% of tile time). Buffer map: tile t -> buf[(t+2)&3]. Stage at tile t
// targets tile t+3 -> buf[(t+1)&3], the buffer read at t-1 (quiescent: all
// waves consumed it -- MFMA data-dependence forces lgkmcnt wait -- before
// crossing t-1's barrier).
// vmcnt ledger (4 loads/thread/stage): pre-loop 4 (tile 2); at iter-t wait,
// 12 in flight {t+1,t+2,t+3}; vmcnt(8) retires exactly tile t+1, read at
// t+1 after the barrier. Tiles 0,1 drained by the phase-1 __syncthreads.
// x loaded NON-TEMPORALLY so the 134 MB x stream does not evict ph from L2.
// ---------------------------------------------------------------------------
__launch_bounds__(512, 2)
__global__ void pc_gemm1(const float* __restrict__ x, const _Float16* __restrict__ ph,
                         int* __restrict__ out, int* __restrict__ c1,
                         int* __restrict__ l1) {
    // 128 KB: [0,64K) x-frag staging (dies) -> B bufs 0,1; [64K,128K) B bufs 2,3.
    __shared__ _Float16 smem[65536];

    const int tid = threadIdx.x;
    const int l = tid & 63;
    const int w = tid >> 6;
    const int wr = w >> 2, wc = w & 3;

    const char* phb = (const char*)ph;
    char* lds = (char*)smem;

    // B-prologue: stage tiles 0,1 into bufs 2,3 (upper 64 KB) NOW, so their L2
    // latency hides under the x-conversion phase. Drained by phase-1 barrier.
#pragma unroll
    for (int tt = 0; tt < 2; ++tt) {
        const char* src = phb + tt * 32768 + w * 1024 + (size_t)l * 16;
        char* dst = lds + (2 + tt) * 32768 + w * 1024;
#pragma unroll
        for (int i = 0; i < 4; ++i)
            __builtin_amdgcn_global_load_lds((const AS1 void*)(src + i * 8192),
                                             (AS3 void*)(dst + i * 8192), 16, 0, 0);
    }

    // Phase 1: x fp32 -> fp16 A-frag order in LDS lower 64 KB (once). NT loads.
    const float* xg = x + (size_t)blockIdx.x * (128 * CELL_DIM);
#pragma unroll
    for (int i = 0; i < 8; ++i) {
        int d = tid + i * 512;            // 4096 half8 dests
        int dl = d & 63, kf = (d >> 6) & 7, rt = d >> 9;
        int row = rt * 16 + (dl & 15);
        int k0 = kf * 32 + (dl >> 4) * 8;
        const f32x4v* s = (const f32x4v*)(xg + row * 256 + k0);
        f32x4v a = __builtin_nontemporal_load(s);
        f32x4v b = __builtin_nontemporal_load(s + 1);
        half8 h;
        h[0] = (_Float16)a[0]; h[1] = (_Float16)a[1];
        h[2] = (_Float16)a[2]; h[3] = (_Float16)a[3];
        h[4] = (_Float16)b[0]; h[5] = (_Float16)b[1];
        h[6] = (_Float16)b[2]; h[7] = (_Float16)b[3];
        *(half8*)(smem + d * 8) = h;
    }
    __syncthreads();   // drains x-frag writes AND B tiles 0,1 (vmcnt 0 here is fine)

    // A-frags to registers: own 64 rows (tiles wr*4 .. wr*4+3), full K.
    half8 A[4][8];
#pragma unroll
    for (int rt = 0; rt < 4; ++rt)
#pragma unroll
        for (int kf = 0; kf < 8; ++kf)
            A[rt][kf] = *(const half8*)(smem + (((wr * 4 + rt) * 8 + kf) * 64 + l) * 8);
    __syncthreads();   // x area dead; lower 64 KB becomes B bufs 0,1

    // Stage tile 2 -> buf 0 (depth-3 pipeline primed: in-flight = tile 2 only).
    {
        const char* src = phb + 2 * 32768 + w * 1024 + (size_t)l * 16;
        char* dst = lds + w * 1024;
#pragma unroll
        for (int i = 0; i < 4; ++i)
            __builtin_amdgcn_global_load_lds((const AS1 void*)(src + i * 8192),
                                             (AS3 void*)(dst + i * 8192), 16, 0, 0);
    }

    float t1[16], t2[16];
    int ic[16];
#pragma unroll
    for (int s = 0; s < 16; ++s) { t1[s] = -FLT_MAX; t2[s] = -FLT_MAX; ic[s] = 0; }

    for (int t = 0; t < 32; ++t) {
        // B frags for this wave's column group from buf[(t+2)&3].
        const char* bp = lds + ((t + 2) & 3) * 32768 + wc * 8192 + l * 16;
        half8 Bf[8];
#pragma unroll
        for (int k = 0; k < 8; ++k)
            Bf[k] = *(const half8*)(bp + k * 1024);

        // Stage tile (t+3)&31 -> buf[(t+1)&3] (read at t-1; all waves past it).
        // Wrapped tail (t>=29) re-stages tiles 0..2 into never-again-read bufs.
        {
            int tn = (t + 3) & 31;
            const char* src = phb + (size_t)tn * 32768 + w * 1024 + (size_t)l * 16;
            char* dst = lds + ((t + 1) & 3) * 32768 + w * 1024;
#pragma unroll
            for (int i = 0; i < 4; ++i)
                __builtin_amdgcn_global_load_lds((const AS1 void*)(src + i * 8192),
                                                 (AS3 void*)(dst + i * 8192), 16, 0, 0);
        }

        f32x4 a0 = {}, a1 = {}, a2 = {}, a3 = {};
        __builtin_amdgcn_s_setprio(1);
#pragma unroll
        for (int k = 0; k < 8; ++k) {
            half8 B = Bf[k];
            a0 = __builtin_amdgcn_mfma_f32_16x16x32_f16(A[0][k], B, a0, 0, 0, 0);
            a1 = __builtin_amdgcn_mfma_f32_16x16x32_f16(A[1][k], B, a1, 0, 0, 0);
            a2 = __builtin_amdgcn_mfma_f32_16x16x32_f16(A[2][k], B, a2, 0, 0, 0);
            a3 = __builtin_amdgcn_mfma_f32_16x16x32_f16(A[3][k], B, a3, 0, 0, 0);
        }
        __builtin_amdgcn_s_setprio(0);
#define UPD(ACC, RT)                                                       \
        _Pragma("unroll")                                                  \
        for (int reg = 0; reg < 4; ++reg) {                                \
            int s = (RT) * 4 + reg;                                        \
            float v = (ACC)[reg];                                          \
            float nt2 = __builtin_amdgcn_fmed3f(t1[s], t2[s], v);          \
            ic[s] = (v > t1[s]) ? t : ic[s];                               \
            t1[s] = fmaxf(t1[s], v);                                       \
            t2[s] = nt2;                                                   \
        }
        UPD(a0, 0) UPD(a1, 1) UPD(a2, 2) UPD(a3, 3)
#undef UPD

        // Counted wait fused with barrier in ONE volatile asm: nothing can be
        // scheduled between them, and the pair is a compiler memory fence.
        // Retires ONLY the oldest tile (t+1); 8 loads stay in flight.
        asm volatile("s_waitcnt vmcnt(8)\n\ts_barrier" ::: "memory");
    }

    // Drain wrapped tail stages before smem is reused for the reduction.
    __syncthreads();

    // Butterfly across the 16 column lanes (masks < 16 keep l>>4 fixed).
    int idx[16];
#pragma unroll
    for (int s = 0; s < 16; ++s) idx[s] = (ic[s] * 4 + wc) * 16 + (l & 15);
#pragma unroll
    for (int m = 1; m <= 8; m <<= 1) {
#pragma unroll
        for (int s = 0; s < 16; ++s) {
            float ot1 = __shfl_xor(t1[s], m, 64);
            int   oi  = __shfl_xor(idx[s], m, 64);
            float ot2 = __shfl_xor(t2[s], m, 64);
            float nt2 = fmaxf(fminf(t1[s], ot1), fmaxf(t2[s], ot2));
            if (ot1 > t1[s] || (ot1 == t1[s] && oi < idx[s])) { t1[s] = ot1; idx[s] = oi; }
            t2[s] = nt2;
        }
    }

    // Per-wave partials -> LDS; combine across col groups.
    float* rT1 = (float*)smem;          // 512
    int*   rI1 = (int*)smem + 512;
    float* rT2 = (float*)smem + 1024;
    if ((l & 15) == 0) {
#pragma unroll
        for (int rt = 0; rt < 4; ++rt)
#pragma unroll
            for (int reg = 0; reg < 4; ++reg) {
                int s = rt * 4 + reg;
                int row = wr * 64 + rt * 16 + (l >> 4) * 4 + reg;
                rT1[row * 4 + wc] = t1[s];
                rI1[row * 4 + wc] = idx[s];
                rT2[row * 4 + wc] = t2[s];
            }
    }
    __syncthreads();
    if (tid < 128) {
        float T1 = -FLT_MAX, T2 = -FLT_MAX; int I1 = 0x7FFFFFFF;
#pragma unroll
        for (int g = 0; g < 4; ++g) {
            float v1 = rT1[tid * 4 + g];
            int   vi = rI1[tid * 4 + g];
            float v2 = rT2[tid * 4 + g];
            float nt2 = fmaxf(fminf(T1, v1), fmaxf(T2, v2));
            if (v1 > T1 || (v1 == T1 && vi < I1)) { T1 = v1; I1 = vi; }
            T2 = nt2;
        }
        int grow = blockIdx.x * 128 + tid;
        out[grow] = I1;
        // Ballot-compacted flag write: 1 atomic per wave (2 per block).
        bool f = (T1 - T2 < M1);
        unsigned long long msk = __ballot(f);
        int cnt = __popcll(msk);
        int prefix = __popcll(msk & ((1ull << l) - 1ull));
        int bpos = 0;
        if (l == 0 && cnt) bpos = atomicAdd(c1, cnt);
        bpos = __shfl(bpos, 0, 64);
        if (f) {
            int pos = bpos + prefix;
            if (pos < CAP1) l1[pos] = grow;
        }
    }
}

// ---------------------------------------------------------------------------
// Kernel B: fp16x2 3-pass MFMA on flagged rows, barrier-free K-loop.
// Grid-stride over 16-row groups (grid 256). 256 thr = 4 waves (wc = col
// group). Per-sim arithmetic IDENTICAL to rounds 3-4 (verified absmax 0).
// ---------------------------------------------------------------------------
__launch_bounds__(256, 2)
__global__ void pc_rescue2(const float* __restrict__ x, const _Float16* __restrict__ ph,
                           const _Float16* __restrict__ pl,
                           const int* __restrict__ c1, const int* __restrict__ l1,
                           int* __restrict__ out, int* __restrict__ c2,
                           int* __restrict__ l2) {
    const int n0 = *c1;
    const int n = n0 < CAP1 ? n0 : CAP1;
    const int G = (n + 15) >> 4;
    const int tid = threadIdx.x;
    const int l = tid & 63, wc = tid >> 6;

    __shared__ float rT1[64];
    __shared__ int   rI1[64];
    __shared__ float rT2[64];

    for (int g = blockIdx.x; g < G; g += gridDim.x) {
        const int base = g * 16;
        __syncthreads();   // protect shared reuse across group iterations

        const int rslot = base + (l & 15);
        const int my_row = l1[rslot < n ? rslot : (n - 1)];

        half8 Ah[8], Al[8];
#pragma unroll
        for (int kf = 0; kf < 8; ++kf) {
            const float* s = x + (size_t)my_row * 256 + kf * 32 + (l >> 4) * 8;
            float4 a = *(const float4*)s, b = *(const float4*)(s + 4);
            float v[8] = {a.x, a.y, a.z, a.w, b.x, b.y, b.z, b.w};
#pragma unroll
            for (int j = 0; j < 8; ++j) {
                _Float16 hi = (_Float16)v[j];
                Ah[kf][j] = hi;
                Al[kf][j] = (_Float16)((v[j] - (float)hi) * 2048.0f);
            }
        }

        const _Float16* bh = ph + wc * 4096 + (size_t)l * 8;
        const _Float16* bl = pl + wc * 4096 + (size_t)l * 8;
        half8 BH[4], BL[4];
#pragma unroll
        for (int j = 0; j < 4; ++j) {
            BH[j] = *(const half8*)(bh + j * 512);
            BL[j] = *(const half8*)(bl + j * 512);
        }

        float t1[4], t2[4];
        int ic[4];
#pragma unroll
        for (int s = 0; s < 4; ++s) { t1[s] = -FLT_MAX; t2[s] = -FLT_MAX; ic[s] = 0; }

        for (int t = 0; t < 32; ++t) {
            const _Float16* bth = bh + t * 16384;
            const _Float16* btl = bl + t * 16384;
            f32x4 hh = {}, hl = {}, lh = {};
#pragma unroll
            for (int k = 0; k < 8; ++k) {
                half8 Bh_ = BH[k & 3], Bl_ = BL[k & 3];
                int off = (k < 4) ? (k + 4) * 512 : (16384 + (k - 4) * 512);
                BH[k & 3] = *(const half8*)(bth + off);
                BL[k & 3] = *(const half8*)(btl + off);
                hh = __builtin_amdgcn_mfma_f32_16x16x32_f16(Ah[k], Bh_, hh, 0, 0, 0);
                hl = __builtin_amdgcn_mfma_f32_16x16x32_f16(Ah[k], Bl_, hl, 0, 0, 0);
                lh = __builtin_amdgcn_mfma_f32_16x16x32_f16(Al[k], Bh_, lh, 0, 0, 0);
            }
#pragma unroll
            for (int reg = 0; reg < 4; ++reg) {
                float v = hh[reg] + (hl[reg] + lh[reg]) * (1.0f / 2048.0f);
                float nt2 = __builtin_amdgcn_fmed3f(t1[reg], t2[reg], v);
                ic[reg] = (v > t1[reg]) ? t : ic[reg];
                t1[reg] = fmaxf(t1[reg], v);
                t2[reg] = nt2;
            }
        }

        int idx[4];
#pragma unroll
        for (int s = 0; s < 4; ++s) idx[s] = (ic[s] * 4 + wc) * 16 + (l & 15);
#pragma unroll
        for (int m = 1; m <= 8; m <<= 1) {
#pragma unroll
            for (int s = 0; s < 4; ++s) {
                float ot1 = __shfl_xor(t1[s], m, 64);
                int   oi  = __shfl_xor(idx[s], m, 64);
                float ot2 = __shfl_xor(t2[s], m, 64);
                float nt2 = fmaxf(fminf(t1[s], ot1), fmaxf(t2[s], ot2));
                if (ot1 > t1[s] || (ot1 == t1[s] && oi < idx[s])) { t1[s] = ot1; idx[s] = oi; }
                t2[s] = nt2;
            }
        }

        if ((l & 15) == 0) {
#pragma unroll
            for (int reg = 0; reg < 4; ++reg) {
                int r = (l >> 4) * 4 + reg;
                rT1[r * 4 + wc] = t1[reg];
                rI1[r * 4 + wc] = idx[reg];
                rT2[r * 4 + wc] = t2[reg];
            }
        }
        __syncthreads();
        if (tid < 16) {
            float T1 = -FLT_MAX, T2 = -FLT_MAX; int I1 = 0x7FFFFFFF;
#pragma unroll
            for (int q = 0; q < 4; ++q) {
                float v1 = rT1[tid * 4 + q];
                int   vi = rI1[tid * 4 + q];
                float v2 = rT2[tid * 4 + q];
                float nt2 = fmaxf(fminf(T1, v1), fmaxf(T2, v2));
                if (v1 > T1 || (v1 == T1 && vi < I1)) { T1 = v1; I1 = vi; }
                T2 = nt2;
            }
            int slot = base + tid;
            if (slot < n) {
                int grow = l1[slot];
                out[grow] = I1;
                if (T1 - T2 < M2) {
                    int pos = atomicAdd(c2, 1);
                    if (pos < CAP2) l2[pos] = grow;
                }
            }
        }
    }
}

// ---------------------------------------------------------------------------
// Kernel C: exact fp32 argmax for residual rows (expected ~30).
// UNCHANGED arithmetic from rounds 2-4 (matches numpy on this dataset).
// ---------------------------------------------------------------------------
__global__ void rescue3(const float* __restrict__ x, const float* __restrict__ p,
                        const int* __restrict__ count, const int* __restrict__ list,
                        int* __restrict__ out) {
    __shared__ float xrow[256];
    __shared__ float pch[32][260];
    __shared__ float red2[32][9];
    __shared__ float bvs[32];
    __shared__ int   bis[32];
    const int tid = threadIdx.x;
    const int n0 = *count;
    const int n = n0 < CAP2 ? n0 : CAP2;
    for (int e = blockIdx.x; e < n; e += gridDim.x) {
        const int row = list[e];
        __syncthreads();
        if (tid < 64) {
            float4 v = *(const float4*)(x + (size_t)row * 256 + tid * 4);
            *(float4*)(&xrow[tid * 4]) = v;
        }
        float bv = -FLT_MAX; int bi = 0;
        const int cell = tid & 31, kq = tid >> 5;
        for (int c0 = 0; c0 < NUM_CELLS; c0 += 32) {
            __syncthreads();
#pragma unroll
            for (int i = 0; i < 8; ++i) {
                int f = tid + i * 256;
                int cr = f >> 6, k4 = (f & 63) * 4;
                float4 v = *(const float4*)(p + (size_t)(c0 + cr) * 256 + k4);
                *(float4*)(&pch[cr][k4]) = v;
            }
            __syncthreads();
            float s = 0.f;
#pragma unroll
            for (int j = 0; j < 8; ++j) {
                float4 pv = *(const float4*)(&pch[cell][kq * 32 + j * 4]);
                float4 xv = *(const float4*)(&xrow[kq * 32 + j * 4]);
                s = fmaf(xv.x, pv.x, s); s = fmaf(xv.y, pv.y, s);
                s = fmaf(xv.z, pv.z, s); s = fmaf(xv.w, pv.w, s);
            }
            red2[cell][kq] = s;
            __syncthreads();
            if (tid < 32) {
                float dot = 0.f;
#pragma unroll
                for (int q = 0; q < 8; ++q) dot += red2[tid][q];
                if (dot > bv) { bv = dot; bi = c0 + tid; }
            }
        }
        if (tid < 32) { bvs[tid] = bv; bis[tid] = bi; }
        __syncthreads();
        if (tid == 0) {
            float B = bvs[0]; int BI = bis[0];
#pragma unroll
            for (int t = 1; t < 32; ++t)
                if (bvs[t] > B || (bvs[t] == B && bis[t] < BI)) { B = bvs[t]; BI = bis[t]; }
            out[row] = BI;
        }
    }
}

// ---------------------------------------------------------------------------
// Fallback (round-1 fp32 vector path) if ws too small.
// ---------------------------------------------------------------------------
#define BM 64
#define BN 64
#define BK 32
#define XP 260
#define PP 68
__launch_bounds__(256, 2)
__global__ void placecells_argmax_fp32(const float* __restrict__ x,
                                       const float* __restrict__ pc,
                                       int* __restrict__ out) {
    __shared__ float xs[BM * XP];
    __shared__ float ps[BK * PP];
    const int tid = threadIdx.x;
    const int tx = tid & 15;
    const int ty = tid >> 4;
    const float* xg = x + (size_t)blockIdx.x * (BM * CELL_DIM);
#pragma unroll
    for (int i = 0; i < 16; ++i) {
        int f = tid + i * 256;
        int s = f >> 6, k4 = (f & 63) << 2;
        *(float4*)(&xs[s * XP + k4]) = *(const float4*)(xg + s * CELL_DIM + k4);
    }
    __syncthreads();
    float runv[4]; int runi[4];
#pragma unroll
    for (int si = 0; si < 4; ++si) { runv[si] = -FLT_MAX; runi[si] = 0; }
    for (int jc = 0; jc < NUM_CELLS; jc += BN) {
        float acc[4][4];
#pragma unroll
        for (int si = 0; si < 4; ++si)
#pragma unroll
            for (int cj = 0; cj < 4; ++cj) acc[si][cj] = 0.0f;
        for (int kc = 0; kc < CELL_DIM; kc += BK) {
            __syncthreads();
#pragma unroll
            for (int i = 0; i < 2; ++i) {
                int f = tid + i * 256;
                int c = f >> 3, k4 = (f & 7) << 2;
                float4 v = *(const float4*)(pc + (size_t)(jc + c) * CELL_DIM + kc + k4);
                ps[(k4 + 0) * PP + c] = v.x; ps[(k4 + 1) * PP + c] = v.y;
                ps[(k4 + 2) * PP + c] = v.z; ps[(k4 + 3) * PP + c] = v.w;
            }
            __syncthreads();
#pragma unroll
            for (int kk = 0; kk < BK; kk += 4) {
                float4 xv[4];
#pragma unroll
                for (int si = 0; si < 4; ++si)
                    xv[si] = *(const float4*)(&xs[(ty * 4 + si) * XP + kc + kk]);
#pragma unroll
                for (int kt = 0; kt < 4; ++kt) {
                    float4 pv = *(const float4*)(&ps[(kk + kt) * PP + tx * 4]);
#pragma unroll
                    for (int si = 0; si < 4; ++si) {
                        float xk = (kt == 0) ? xv[si].x : (kt == 1) ? xv[si].y :
                                   (kt == 2) ? xv[si].z : xv[si].w;
                        acc[si][0] = fmaf(xk, pv.x, acc[si][0]);
                        acc[si][1] = fmaf(xk, pv.y, acc[si][1]);
                        acc[si][2] = fmaf(xk, pv.z, acc[si][2]);
                        acc[si][3] = fmaf(xk, pv.w, acc[si][3]);
                    }
                }
            }
        }
#pragma unroll
        for (int si = 0; si < 4; ++si)
#pragma unroll
            for (int cj = 0; cj < 4; ++cj) {
                int idx = jc + tx * 4 + cj;
                if (acc[si][cj] > runv[si]) { runv[si] = acc[si][cj]; runi[si] = idx; }
            }
    }
    __syncthreads();
    float* rv = ps; int* ri = (int*)(ps + 1024);
#pragma unroll
    for (int si = 0; si < 4; ++si) {
        int s = ty * 4 + si;
        rv[s * 16 + tx] = runv[si]; ri[s * 16 + tx] = runi[si];
    }
    __syncthreads();
    if (tid < BM) {
        float bv = rv[tid * 16]; int bi = ri[tid * 16];
#pragma unroll
        for (int t = 1; t < 16; ++t) {
            float v = rv[tid * 16 + t]; int i = ri[tid * 16 + t];
            if (v > bv || (v == bv && i < bi)) { bv = v; bi = i; }
        }
        out[(size_t)blockIdx.x * BM + tid] = bi;
    }
}

extern "C" void kernel_launch(void* const* d_in, const int* in_sizes, int n_in,
                              void* d_out, int out_size, void* d_ws, size_t ws_size,
                              hipStream_t stream) {
    const float* x  = (const float*)d_in[0];   // (131072, 256) fp32
    const float* pc = (const float*)d_in[1];   // (2048, 256) fp32
    int* out = (int*)d_out;

    if (ws_size >= (size_t)WS_NEEDED) {
        char* ws = (char*)d_ws;
        int* c1 = (int*)(ws + WS_C1);
        int* c2 = (int*)(ws + WS_C2);
        int* l1 = (int*)(ws + WS_L1);
        int* l2 = (int*)(ws + WS_L2);
        _Float16* ph = (_Float16*)(ws + WS_PH);
        _Float16* pl = (_Float16*)(ws + WS_PL);
        prep_p<<<256, 256, 0, stream>>>(pc, ph, pl, c1, c2);
        pc_gemm1<<<N_STATES / 128, 512, 0, stream>>>(x, ph, out, c1, l1);
        pc_rescue2<<<256, 256, 0, stream>>>(x, ph, pl, c1, l1, out, c2, l2);
        rescue3<<<64, 256, 0, stream>>>(x, pc, c2, l2, out);
    } else {
        placecells_argmax_fp32<<<N_STATES / BM, 256, 0, stream>>>(x, pc, out);
    }
}

// Round 4
// 484.518 us; speedup vs baseline: 1.0005x; 1.0005x over previous
//
#include <hip/hip_runtime.h>
#include <float.h>
#include <stdint.h>

#define NUM_CELLS 2048
#define CELL_DIM  256
#define N_STATES  131072

typedef _Float16 half8 __attribute__((ext_vector_type(8)));
typedef float    f32x4 __attribute__((ext_vector_type(4)));
typedef float    f32x4v __attribute__((ext_vector_type(4)));   // nt-load-able

// Stage-1 (1-pass fp16) sim-difference noise sigma ~6e-3; M1 ~ 17 sigma.
#define M1 0.10f
// Stage-2 (fp16x2 3-pass) noise sigma ~1.5e-5; M2 = 0.0008 ~ 50 sigma.
#define M2 0.0008f
#define CAP1 32768
#define CAP2 4096

// ws layout (bytes). ws_size >= WS_NEEDED confirmed (rounds 2-4 ran this path).
#define WS_C1 0
#define WS_C2 4
#define WS_L1 1024
#define WS_L2 (WS_L1 + 4 * CAP1)                    // 132096
#define WS_PH 262144
#define WS_PL (WS_PH + 1048576)
// 128 KB slack after pl retained (layout unchanged from verified rounds).
#define WS_NEEDED (WS_PL + 1048576 + 131072)        // 2490368

#define AS1 __attribute__((address_space(1)))
#define AS3 __attribute__((address_space(3)))

// ---------------------------------------------------------------------------
// Prep: p fp32 -> B-fragment-order fp16 hi + (lo*2048) arrays; zero counters.
// Frag order (16x16x32 f16 B): half8 index d = (ct*8 + kf)*64 + l, where
// cell = ct*16 + (l&15), k = kf*32 + (l>>4)*8 + j.
// ---------------------------------------------------------------------------
__global__ void prep_p(const float* __restrict__ p, _Float16* __restrict__ ph,
                       _Float16* __restrict__ pl, int* __restrict__ c1,
                       int* __restrict__ c2) {
    int d = blockIdx.x * 256 + threadIdx.x;   // 65536 dests
    if (d == 0) { *c1 = 0; *c2 = 0; }
    int l = d & 63, kf = (d >> 6) & 7, ct = d >> 9;
    int cell = ct * 16 + (l & 15);
    int k0 = kf * 32 + (l >> 4) * 8;
    const float* s = p + cell * 256 + k0;
    float4 a = *(const float4*)s, b = *(const float4*)(s + 4);
    float v[8] = {a.x, a.y, a.z, a.w, b.x, b.y, b.z, b.w};
    half8 h, lo;
#pragma unroll
    for (int j = 0; j < 8; ++j) {
        _Float16 hi = (_Float16)v[j];
        h[j] = hi;
        lo[j] = (_Float16)((v[j] - (float)hi) * 2048.0f);  // scaled: no fp16 denorms
    }
    *(half8*)(ph + (size_t)d * 8) = h;
    *(half8*)(pl + (size_t)d * 8) = lo;
}

// ---------------------------------------------------------------------------
// Kernel A: 1-pass fp16 MFMA GEMM with in-place LDS->VGPR B-rotation.
// Block = 128 rows; 512 thr = 8 waves (wr 0..1 row half x wc 0..3 col group).
// A-frags (64 rows x K=256) = 128 VGPRs; total regs/wave ~256 -> hard 2
// waves/SIMD, so ILP must come from within the wave:
//  - B frags for tile t are ALREADY IN REGISTERS when tile t's cluster
//    starts: during tile t's MFMAs, after the 4 MFMAs consuming Bf[k], we
//    overwrite Bf[k] with tile t+1's frag k (ds_read from the 4x32KB ring).
//    The reads run on the LDS pipe UNDER the matrix pipe -- this removes the
//    per-tile post-barrier 64x ds_read_b128 burst + lgkm wait that R0-R3
//    all shared (the ~60% issue-idle the counters showed).
//  - Ring staged via global_load_lds, depth-3; per-tile wait is the fused
//    "s_waitcnt vmcnt(4); s_barrier": retires tiles t+1 AND t+2, so tile
//    t+1 is LDS-resident at tile t's start (prefetch-read legality), while
//    tile t+3's stage stays in flight across the barrier (never vmcnt(0)).
// vmcnt ledger (4 loads/thread/stage): pre-loop {2}; iter t: issue t+3 ->
// {t+2,t+3}=8 in flight; vmcnt(4) retires t+2. Tiles 0,1 staged in the
// prologue and drained by the phase-1 __syncthreads. Buffer map: tile tau
// -> buf[(tau+2)&3]; stage at t targets buf[(t+1)&3] = tile t-1's buffer,
// whose reads (prefetched at t-2) completed before t-1's MFMAs ended.
// x loaded NON-TEMPORALLY so the 134 MB x stream does not evict ph from L2.
// ---------------------------------------------------------------------------
__launch_bounds__(512, 2)
__global__ void pc_gemm1(const float* __restrict__ x, const _Float16* __restrict__ ph,
                         int* __restrict__ out, int* __restrict__ c1,
                         int* __restrict__ l1) {
    // 128 KB: [0,64K) x-frag staging (dies) -> B bufs 0,1; [64K,128K) B bufs 2,3.
    __shared__ _Float16 smem[65536];

    const int tid = threadIdx.x;
    const int l = tid & 63;
    const int w = tid >> 6;
    const int wr = w >> 2, wc = w & 3;

    const char* phb = (const char*)ph;
    char* lds = (char*)smem;

    // B-prologue: stage tiles 0,1 into bufs 2,3 (upper 64 KB) NOW, so their L2
    // latency hides under the x-conversion phase. Drained by phase-1 barrier.
#pragma unroll
    for (int tt = 0; tt < 2; ++tt) {
        const char* src = phb + tt * 32768 + w * 1024 + (size_t)l * 16;
        char* dst = lds + (2 + tt) * 32768 + w * 1024;
#pragma unroll
        for (int i = 0; i < 4; ++i)
            __builtin_amdgcn_global_load_lds((const AS1 void*)(src + i * 8192),
                                             (AS3 void*)(dst + i * 8192), 16, 0, 0);
    }

    // Phase 1: x fp32 -> fp16 A-frag order in LDS lower 64 KB (once). NT loads.
    const float* xg = x + (size_t)blockIdx.x * (128 * CELL_DIM);
#pragma unroll
    for (int i = 0; i < 8; ++i) {
        int d = tid + i * 512;            // 4096 half8 dests
        int dl = d & 63, kf = (d >> 6) & 7, rt = d >> 9;
        int row = rt * 16 + (dl & 15);
        int k0 = kf * 32 + (dl >> 4) * 8;
        const f32x4v* s = (const f32x4v*)(xg + row * 256 + k0);
        f32x4v a = __builtin_nontemporal_load(s);
        f32x4v b = __builtin_nontemporal_load(s + 1);
        half8 h;
        h[0] = (_Float16)a[0]; h[1] = (_Float16)a[1];
        h[2] = (_Float16)a[2]; h[3] = (_Float16)a[3];
        h[4] = (_Float16)b[0]; h[5] = (_Float16)b[1];
        h[6] = (_Float16)b[2]; h[7] = (_Float16)b[3];
        *(half8*)(smem + d * 8) = h;
    }
    __syncthreads();   // drains x-frag writes AND B tiles 0,1 (vmcnt 0 here is fine)

    // A-frags to registers: own 64 rows (tiles wr*4 .. wr*4+3), full K.
    half8 A[4][8];
#pragma unroll
    for (int rt = 0; rt < 4; ++rt)
#pragma unroll
        for (int kf = 0; kf < 8; ++kf)
            A[rt][kf] = *(const half8*)(smem + (((wr * 4 + rt) * 8 + kf) * 64 + l) * 8);
    __syncthreads();   // x area dead; lower 64 KB becomes B bufs 0,1

    // Stage tile 2 -> buf 0 (in-flight = tile 2 only = 4 loads/thread).
    {
        const char* src = phb + 2 * 32768 + w * 1024 + (size_t)l * 16;
        char* dst = lds + w * 1024;
#pragma unroll
        for (int i = 0; i < 4; ++i)
            __builtin_amdgcn_global_load_lds((const AS1 void*)(src + i * 8192),
                                             (AS3 void*)(dst + i * 8192), 16, 0, 0);
    }

    // Pre-load tile 0's B frags into registers (buf 2, already drained).
    const int boff = wc * 8192 + l * 16;   // per-lane offset within a buffer
    half8 Bf[8];
    {
        const char* bp = lds + 2 * 32768 + boff;
#pragma unroll
        for (int k = 0; k < 8; ++k)
            Bf[k] = *(const half8*)(bp + k * 1024);
    }

    float t1[16], t2[16];
    int ic[16];
#pragma unroll
    for (int s = 0; s < 16; ++s) { t1[s] = -FLT_MAX; t2[s] = -FLT_MAX; ic[s] = 0; }

    for (int t = 0; t < 32; ++t) {
        // Stage tile (t+3)&31 -> buf[(t+1)&3] (tile t-1's buffer; its reads
        // -- the prefetch at t-2 -- completed before t-1's MFMAs finished).
        // Wrapped tail (t>=29) re-stages tiles 0..2 into never-read bufs.
        {
            int tn = (t + 3) & 31;
            const char* src = phb + (size_t)tn * 32768 + w * 1024 + (size_t)l * 16;
            char* dst = lds + ((t + 1) & 3) * 32768 + w * 1024;
#pragma unroll
            for (int i = 0; i < 4; ++i)
                __builtin_amdgcn_global_load_lds((const AS1 void*)(src + i * 8192),
                                                 (AS3 void*)(dst + i * 8192), 16, 0, 0);
        }

        // Tile t+1's frags live in buf[(t+3)&3]; LDS-resident since the
        // vmcnt(4) wait at iter t-1 (prologue sync for t=0,1).
        const char* nbp = lds + ((t + 3) & 3) * 32768 + boff;

        f32x4 a0 = {}, a1 = {}, a2 = {}, a3 = {};
#pragma unroll
        for (int k = 0; k < 8; ++k) {
            a0 = __builtin_amdgcn_mfma_f32_16x16x32_f16(A[0][k], Bf[k], a0, 0, 0, 0);
            a1 = __builtin_amdgcn_mfma_f32_16x16x32_f16(A[1][k], Bf[k], a1, 0, 0, 0);
            a2 = __builtin_amdgcn_mfma_f32_16x16x32_f16(A[2][k], Bf[k], a2, 0, 0, 0);
            a3 = __builtin_amdgcn_mfma_f32_16x16x32_f16(A[3][k], Bf[k], a3, 0, 0, 0);
            // In-place rotation: after the last use of Bf[k] this tile,
            // refill it with tile t+1's frag k (LDS pipe under matrix pipe).
            Bf[k] = *(const half8*)(nbp + k * 1024);
        }
#define UPD(ACC, RT)                                                       \
        _Pragma("unroll")                                                  \
        for (int reg = 0; reg < 4; ++reg) {                                \
            int s = (RT) * 4 + reg;                                        \
            float v = (ACC)[reg];                                          \
            float nt2 = __builtin_amdgcn_fmed3f(t1[s], t2[s], v);          \
            ic[s] = (v > t1[s]) ? t : ic[s];                               \
            t1[s] = fmaxf(t1[s], v);                                       \
            t2[s] = nt2;                                                   \
        }
        UPD(a0, 0) UPD(a1, 1) UPD(a2, 2) UPD(a3, 3)
#undef UPD

        // Counted wait fused with barrier (one volatile asm = compiler fence):
        // retires tiles t+1,t+2 (so t+1 is readable NOW and t+2 next iter);
        // tile t+3's stage stays in flight across the barrier.
        asm volatile("s_waitcnt vmcnt(4)\n\ts_barrier" ::: "memory");
    }

    // Drain the wrapped tail stage before smem is reused for the reduction.
    __syncthreads();

    // Butterfly across the 16 column lanes (masks < 16 keep l>>4 fixed).
    int idx[16];
#pragma unroll
    for (int s = 0; s < 16; ++s) idx[s] = (ic[s] * 4 + wc) * 16 + (l & 15);
#pragma unroll
    for (int m = 1; m <= 8; m <<= 1) {
#pragma unroll
        for (int s = 0; s < 16; ++s) {
            float ot1 = __shfl_xor(t1[s], m, 64);
            int   oi  = __shfl_xor(idx[s], m, 64);
            float ot2 = __shfl_xor(t2[s], m, 64);
            float nt2 = fmaxf(fminf(t1[s], ot1), fmaxf(t2[s], ot2));
            if (ot1 > t1[s] || (ot1 == t1[s] && oi < idx[s])) { t1[s] = ot1; idx[s] = oi; }
            t2[s] = nt2;
        }
    }

    // Per-wave partials -> LDS; combine across col groups.
    float* rT1 = (float*)smem;          // 512
    int*   rI1 = (int*)smem + 512;
    float* rT2 = (float*)smem + 1024;
    if ((l & 15) == 0) {
#pragma unroll
        for (int rt = 0; rt < 4; ++rt)
#pragma unroll
            for (int reg = 0; reg < 4; ++reg) {
                int s = rt * 4 + reg;
                int row = wr * 64 + rt * 16 + (l >> 4) * 4 + reg;
                rT1[row * 4 + wc] = t1[s];
                rI1[row * 4 + wc] = idx[s];
                rT2[row * 4 + wc] = t2[s];
            }
    }
    __syncthreads();
    if (tid < 128) {
        float T1 = -FLT_MAX, T2 = -FLT_MAX; int I1 = 0x7FFFFFFF;
#pragma unroll
        for (int g = 0; g < 4; ++g) {
            float v1 = rT1[tid * 4 + g];
            int   vi = rI1[tid * 4 + g];
            float v2 = rT2[tid * 4 + g];
            float nt2 = fmaxf(fminf(T1, v1), fmaxf(T2, v2));
            if (v1 > T1 || (v1 == T1 && vi < I1)) { T1 = v1; I1 = vi; }
            T2 = nt2;
        }
        int grow = blockIdx.x * 128 + tid;
        out[grow] = I1;
        // Ballot-compacted flag write: 1 atomic per wave (2 per block).
        bool f = (T1 - T2 < M1);
        unsigned long long msk = __ballot(f);
        int cnt = __popcll(msk);
        int prefix = __popcll(msk & ((1ull << l) - 1ull));
        int bpos = 0;
        if (l == 0 && cnt) bpos = atomicAdd(c1, cnt);
        bpos = __shfl(bpos, 0, 64);
        if (f) {
            int pos = bpos + prefix;
            if (pos < CAP1) l1[pos] = grow;
        }
    }
}

// ---------------------------------------------------------------------------
// Kernel B: fp16x2 3-pass MFMA on flagged rows, barrier-free K-loop.
// Grid-stride over 16-row groups (grid 256). 256 thr = 4 waves (wc = col
// group). Per-sim arithmetic IDENTICAL to rounds 3-4 (verified absmax 0).
// ---------------------------------------------------------------------------
__launch_bounds__(256, 2)
__global__ void pc_rescue2(const float* __restrict__ x, const _Float16* __restrict__ ph,
                           const _Float16* __restrict__ pl,
                           const int* __restrict__ c1, const int* __restrict__ l1,
                           int* __restrict__ out, int* __restrict__ c2,
                           int* __restrict__ l2) {
    const int n0 = *c1;
    const int n = n0 < CAP1 ? n0 : CAP1;
    const int G = (n + 15) >> 4;
    const int tid = threadIdx.x;
    const int l = tid & 63, wc = tid >> 6;

    __shared__ float rT1[64];
    __shared__ int   rI1[64];
    __shared__ float rT2[64];

    for (int g = blockIdx.x; g < G; g += gridDim.x) {
        const int base = g * 16;
        __syncthreads();   // protect shared reuse across group iterations

        const int rslot = base + (l & 15);
        const int my_row = l1[rslot < n ? rslot : (n - 1)];

        half8 Ah[8], Al[8];
#pragma unroll
        for (int kf = 0; kf < 8; ++kf) {
            const float* s = x + (size_t)my_row * 256 + kf * 32 + (l >> 4) * 8;
            float4 a = *(const float4*)s, b = *(const float4*)(s + 4);
            float v[8] = {a.x, a.y, a.z, a.w, b.x, b.y, b.z, b.w};
#pragma unroll
            for (int j = 0; j < 8; ++j) {
                _Float16 hi = (_Float16)v[j];
                Ah[kf][j] = hi;
                Al[kf][j] = (_Float16)((v[j] - (float)hi) * 2048.0f);
            }
        }

        const _Float16* bh = ph + wc * 4096 + (size_t)l * 8;
        const _Float16* bl = pl + wc * 4096 + (size_t)l * 8;
        half8 BH[4], BL[4];
#pragma unroll
        for (int j = 0; j < 4; ++j) {
            BH[j] = *(const half8*)(bh + j * 512);
            BL[j] = *(const half8*)(bl + j * 512);
        }

        float t1[4], t2[4];
        int ic[4];
#pragma unroll
        for (int s = 0; s < 4; ++s) { t1[s] = -FLT_MAX; t2[s] = -FLT_MAX; ic[s] = 0; }

        for (int t = 0; t < 32; ++t) {
            const _Float16* bth = bh + t * 16384;
            const _Float16* btl = bl + t * 16384;
            f32x4 hh = {}, hl = {}, lh = {};
#pragma unroll
            for (int k = 0; k < 8; ++k) {
                half8 Bh_ = BH[k & 3], Bl_ = BL[k & 3];
                int off = (k < 4) ? (k + 4) * 512 : (16384 + (k - 4) * 512);
                BH[k & 3] = *(const half8*)(bth + off);
                BL[k & 3] = *(const half8*)(btl + off);
                hh = __builtin_amdgcn_mfma_f32_16x16x32_f16(Ah[k], Bh_, hh, 0, 0, 0);
                hl = __builtin_amdgcn_mfma_f32_16x16x32_f16(Ah[k], Bl_, hl, 0, 0, 0);
                lh = __builtin_amdgcn_mfma_f32_16x16x32_f16(Al[k], Bh_, lh, 0, 0, 0);
            }
#pragma unroll
            for (int reg = 0; reg < 4; ++reg) {
                float v = hh[reg] + (hl[reg] + lh[reg]) * (1.0f / 2048.0f);
                float nt2 = __builtin_amdgcn_fmed3f(t1[reg], t2[reg], v);
                ic[reg] = (v > t1[reg]) ? t : ic[reg];
                t1[reg] = fmaxf(t1[reg], v);
                t2[reg] = nt2;
            }
        }

        int idx[4];
#pragma unroll
        for (int s = 0; s < 4; ++s) idx[s] = (ic[s] * 4 + wc) * 16 + (l & 15);
#pragma unroll
        for (int m = 1; m <= 8; m <<= 1) {
#pragma unroll
            for (int s = 0; s < 4; ++s) {
                float ot1 = __shfl_xor(t1[s], m, 64);
                int   oi  = __shfl_xor(idx[s], m, 64);
                float ot2 = __shfl_xor(t2[s], m, 64);
                float nt2 = fmaxf(fminf(t1[s], ot1), fmaxf(t2[s], ot2));
                if (ot1 > t1[s] || (ot1 == t1[s] && oi < idx[s])) { t1[s] = ot1; idx[s] = oi; }
                t2[s] = nt2;
            }
        }

        if ((l & 15) == 0) {
#pragma unroll
            for (int reg = 0; reg < 4; ++reg) {
                int r = (l >> 4) * 4 + reg;
                rT1[r * 4 + wc] = t1[reg];
                rI1[r * 4 + wc] = idx[reg];
                rT2[r * 4 + wc] = t2[reg];
            }
        }
        __syncthreads();
        if (tid < 16) {
            float T1 = -FLT_MAX, T2 = -FLT_MAX; int I1 = 0x7FFFFFFF;
#pragma unroll
            for (int q = 0; q < 4; ++q) {
                float v1 = rT1[tid * 4 + q];
                int   vi = rI1[tid * 4 + q];
                float v2 = rT2[tid * 4 + q];
                float nt2 = fmaxf(fminf(T1, v1), fmaxf(T2, v2));
                if (v1 > T1 || (v1 == T1 && vi < I1)) { T1 = v1; I1 = vi; }
                T2 = nt2;
            }
            int slot = base + tid;
            if (slot < n) {
                int grow = l1[slot];
                out[grow] = I1;
                if (T1 - T2 < M2) {
                    int pos = atomicAdd(c2, 1);
                    if (pos < CAP2) l2[pos] = grow;
                }
            }
        }
    }
}

// ---------------------------------------------------------------------------
// Kernel C: exact fp32 argmax for residual rows (expected ~30).
// UNCHANGED arithmetic from rounds 2-4 (matches numpy on this dataset).
// ---------------------------------------------------------------------------
__global__ void rescue3(const float* __restrict__ x, const float* __restrict__ p,
                        const int* __restrict__ count, const int* __restrict__ list,
                        int* __restrict__ out) {
    __shared__ float xrow[256];
    __shared__ float pch[32][260];
    __shared__ float red2[32][9];
    __shared__ float bvs[32];
    __shared__ int   bis[32];
    const int tid = threadIdx.x;
    const int n0 = *count;
    const int n = n0 < CAP2 ? n0 : CAP2;
    for (int e = blockIdx.x; e < n; e += gridDim.x) {
        const int row = list[e];
        __syncthreads();
        if (tid < 64) {
            float4 v = *(const float4*)(x + (size_t)row * 256 + tid * 4);
            *(float4*)(&xrow[tid * 4]) = v;
        }
        float bv = -FLT_MAX; int bi = 0;
        const int cell = tid & 31, kq = tid >> 5;
        for (int c0 = 0; c0 < NUM_CELLS; c0 += 32) {
            __syncthreads();
#pragma unroll
            for (int i = 0; i < 8; ++i) {
                int f = tid + i * 256;
                int cr = f >> 6, k4 = (f & 63) * 4;
                float4 v = *(const float4*)(p + (size_t)(c0 + cr) * 256 + k4);
                *(float4*)(&pch[cr][k4]) = v;
            }
            __syncthreads();
            float s = 0.f;
#pragma unroll
            for (int j = 0; j < 8; ++j) {
                float4 pv = *(const float4*)(&pch[cell][kq * 32 + j * 4]);
                float4 xv = *(const float4*)(&xrow[kq * 32 + j * 4]);
                s = fmaf(xv.x, pv.x, s); s = fmaf(xv.y, pv.y, s);
                s = fmaf(xv.z, pv.z, s); s = fmaf(xv.w, pv.w, s);
            }
            red2[cell][kq] = s;
            __syncthreads();
            if (tid < 32) {
                float dot = 0.f;
#pragma unroll
                for (int q = 0; q < 8; ++q) dot += red2[tid][q];
                if (dot > bv) { bv = dot; bi = c0 + tid; }
            }
        }
        if (tid < 32) { bvs[tid] = bv; bis[tid] = bi; }
        __syncthreads();
        if (tid == 0) {
            float B = bvs[0]; int BI = bis[0];
#pragma unroll
            for (int t = 1; t < 32; ++t)
                if (bvs[t] > B || (bvs[t] == B && bis[t] < BI)) { B = bvs[t]; BI = bis[t]; }
            out[row] = BI;
        }
    }
}

// ---------------------------------------------------------------------------
// Fallback (round-1 fp32 vector path) if ws too small.
// ---------------------------------------------------------------------------
#define BM 64
#define BN 64
#define BK 32
#define XP 260
#define PP 68
__launch_bounds__(256, 2)
__global__ void placecells_argmax_fp32(const float* __restrict__ x,
                                       const float* __restrict__ pc,
                                       int* __restrict__ out) {
    __shared__ float xs[BM * XP];
    __shared__ float ps[BK * PP];
    const int tid = threadIdx.x;
    const int tx = tid & 15;
    const int ty = tid >> 4;
    const float* xg = x + (size_t)blockIdx.x * (BM * CELL_DIM);
#pragma unroll
    for (int i = 0; i < 16; ++i) {
        int f = tid + i * 256;
        int s = f >> 6, k4 = (f & 63) << 2;
        *(float4*)(&xs[s * XP + k4]) = *(const float4*)(xg + s * CELL_DIM + k4);
    }
    __syncthreads();
    float runv[4]; int runi[4];
#pragma unroll
    for (int si = 0; si < 4; ++si) { runv[si] = -FLT_MAX; runi[si] = 0; }
    for (int jc = 0; jc < NUM_CELLS; jc += BN) {
        float acc[4][4];
#pragma unroll
        for (int si = 0; si < 4; ++si)
#pragma unroll
            for (int cj = 0; cj < 4; ++cj) acc[si][cj] = 0.0f;
        for (int kc = 0; kc < CELL_DIM; kc += BK) {
            __syncthreads();
#pragma unroll
            for (int i = 0; i < 2; ++i) {
                int f = tid + i * 256;
                int c = f >> 3, k4 = (f & 7) << 2;
                float4 v = *(const float4*)(pc + (size_t)(jc + c) * CELL_DIM + kc + k4);
                ps[(k4 + 0) * PP + c] = v.x; ps[(k4 + 1) * PP + c] = v.y;
                ps[(k4 + 2) * PP + c] = v.z; ps[(k4 + 3) * PP + c] = v.w;
            }
            __syncthreads();
#pragma unroll
            for (int kk = 0; kk < BK; kk += 4) {
                float4 xv[4];
#pragma unroll
                for (int si = 0; si < 4; ++si)
                    xv[si] = *(const float4*)(&xs[(ty * 4 + si) * XP + kc + kk]);
#pragma unroll
                for (int kt = 0; kt < 4; ++kt) {
                    float4 pv = *(const float4*)(&ps[(kk + kt) * PP + tx * 4]);
#pragma unroll
                    for (int si = 0; si < 4; ++si) {
                        float xk = (kt == 0) ? xv[si].x : (kt == 1) ? xv[si].y :
                                   (kt == 2) ? xv[si].z : xv[si].w;
                        acc[si][0] = fmaf(xk, pv.x, acc[si][0]);
                        acc[si][1] = fmaf(xk, pv.y, acc[si][1]);
                        acc[si][2] = fmaf(xk, pv.z, acc[si][2]);
                        acc[si][3] = fmaf(xk, pv.w, acc[si][3]);
                    }
                }
            }
        }
#pragma unroll
        for (int si = 0; si < 4; ++si)
#pragma unroll
            for (int cj = 0; cj < 4; ++cj) {
                int idx = jc + tx * 4 + cj;
                if (acc[si][cj] > runv[si]) { runv[si] = acc[si][cj]; runi[si] = idx; }
            }
    }
    __syncthreads();
    float* rv = ps; int* ri = (int*)(ps + 1024);
#pragma unroll
    for (int si = 0; si < 4; ++si) {
        int s = ty * 4 + si;
        rv[s * 16 + tx] = runv[si]; ri[s * 16 + tx] = runi[si];
    }
    __syncthreads();
    if (tid < BM) {
        float bv = rv[tid * 16]; int bi = ri[tid * 16];
#pragma unroll
        for (int t = 1; t < 16; ++t) {
            float v = rv[tid * 16 + t]; int i = ri[tid * 16 + t];
            if (v > bv || (v == bv && i < bi)) { bv = v; bi = i; }
        }
        out[(size_t)blockIdx.x * BM + tid] = bi;
    }
}

extern "C" void kernel_launch(void* const* d_in, const int* in_sizes, int n_in,
                              void* d_out, int out_size, void* d_ws, size_t ws_size,
                              hipStream_t stream) {
    const float* x  = (const float*)d_in[0];   // (131072, 256) fp32
    const float* pc = (const float*)d_in[1];   // (2048, 256) fp32
    int* out = (int*)d_out;

    if (ws_size >= (size_t)WS_NEEDED) {
        char* ws = (char*)d_ws;
        int* c1 = (int*)(ws + WS_C1);
        int* c2 = (int*)(ws + WS_C2);
        int* l1 = (int*)(ws + WS_L1);
        int* l2 = (int*)(ws + WS_L2);
        _Float16* ph = (_Float16*)(ws + WS_PH);
        _Float16* pl = (_Float16*)(ws + WS_PL);
        prep_p<<<256, 256, 0, stream>>>(pc, ph, pl, c1, c2);
        pc_gemm1<<<N_STATES / 128, 512, 0, stream>>>(x, ph, out, c1, l1);
        pc_rescue2<<<256, 256, 0, stream>>>(x, ph, pl, c1, l1, out, c2, l2);
        rescue3<<<64, 256, 0, stream>>>(x, pc, c2, l2, out);
    } else {
        placecells_argmax_fp32<<<N_STATES / BM, 256, 0, stream>>>(x, pc, out);
    }
}

// Round 5
// 444.152 us; speedup vs baseline: 1.0914x; 1.0909x over previous
//
#include <hip/hip_runtime.h>
#include <float.h>
#include <stdint.h>

#define NUM_CELLS 2048
#define CELL_DIM  256
#define N_STATES  131072

typedef _Float16 half8 __attribute__((ext_vector_type(8)));
typedef float    f32x4 __attribute__((ext_vector_type(4)));
typedef float    f32x4v __attribute__((ext_vector_type(4)));   // nt-load-able

// Stage-1 (1-pass fp16) sim-difference noise sigma ~6e-3; M1 ~ 17 sigma.
#define M1 0.10f
// Stage-2 (fp16x2 3-pass) noise sigma ~1.5e-5; M2 = 0.0008 ~ 50 sigma.
#define M2 0.0008f
#define CAP1 32768
#define CAP2 4096

// ws layout (bytes). ws_size >= WS_NEEDED confirmed (rounds 2-4 ran this path).
#define WS_C1 0
#define WS_C2 4
#define WS_L1 1024
#define WS_L2 (WS_L1 + 4 * CAP1)                    // 132096
#define WS_PH 262144
#define WS_PL (WS_PH + 1048576)
// 128 KB slack after pl retained (layout unchanged from verified rounds).
#define WS_NEEDED (WS_PL + 1048576 + 131072)        // 2490368

#define AS1 __attribute__((address_space(1)))
#define AS3 __attribute__((address_space(3)))

// ---------------------------------------------------------------------------
// Prep: p fp32 -> B-fragment-order fp16 hi + (lo*2048) arrays; zero counters.
// Frag order (16x16x32 f16 B): half8 index d = (ct*8 + kf)*64 + l, where
// cell = ct*16 + (l&15), k = kf*32 + (l>>4)*8 + j.
// ---------------------------------------------------------------------------
__global__ void prep_p(const float* __restrict__ p, _Float16* __restrict__ ph,
                       _Float16* __restrict__ pl, int* __restrict__ c1,
                       int* __restrict__ c2) {
    int d = blockIdx.x * 256 + threadIdx.x;   // 65536 dests
    if (d == 0) { *c1 = 0; *c2 = 0; }
    int l = d & 63, kf = (d >> 6) & 7, ct = d >> 9;
    int cell = ct * 16 + (l & 15);
    int k0 = kf * 32 + (l >> 4) * 8;
    const float* s = p + cell * 256 + k0;
    float4 a = *(const float4*)s, b = *(const float4*)(s + 4);
    float v[8] = {a.x, a.y, a.z, a.w, b.x, b.y, b.z, b.w};
    half8 h, lo;
#pragma unroll
    for (int j = 0; j < 8; ++j) {
        _Float16 hi = (_Float16)v[j];
        h[j] = hi;
        lo[j] = (_Float16)((v[j] - (float)hi) * 2048.0f);  // scaled: no fp16 denorms
    }
    *(half8*)(ph + (size_t)d * 8) = h;
    *(half8*)(pl + (size_t)d * 8) = lo;
}

// ---------------------------------------------------------------------------
// Kernel A (R5 restructure): 1-pass fp16 MFMA GEMM, 4-wave blocks, 2 blocks/CU.
// R0-R4 post-mortem: four B-feed strategies all ~210us, MfmaUtil ~29% -- the
// ~55% idle was the MONO-BLOCK LOCKSTEP (8 waves in one barrier group: during
// UPD/barrier/x-phase/reduce the MFMA pipe has no other wave), not the B-feed.
// New structure:
//  - Block = 256 thr = 4 waves; wave w owns rows [blk*128+w*32, +32) OUTRIGHT
//    and sweeps ALL 2048 cells -> no cross-wave reduction, no reduce barriers.
//  - A-frags loaded per-lane DIRECTLY from x (same addresses + fp16 rounding
//    as the old LDS staging path -> bit-identical), converted in regs. No
//    phase-1, no x-LDS. A=64 VGPRs/wave; total ~200 -> 2 waves/SIMD.
//  - LDS = 4 x 16 KB B-slab ring only (64 KB/block) -> TWO blocks resident
//    per CU. The two blocks are independent: their phases interleave, so one
//    block's barrier/UPD idle is filled by the other's MFMAs.
//  - Slab (16 KB) = 32 cells x full K in frag order. Per slab per wave:
//    2 row-tiles x 2 col-tiles x 8 kf = 32 MFMAs, in-place Bf rotation
//    (refill Bf[ct][k] with slab t+1 right after its last use).
//  - Staging 3-ahead via global_load_lds; per-slab fused "s_waitcnt vmcnt(4);
//    s_barrier" retires exactly slab t+2 (rotation needs t+1 resident at top
//    of t); 4 loads stay in flight across the barrier. Wrap tail re-stages
//    slabs 0.. into buffers that are never consumed (reads at t=63 discard).
// vmcnt ledger (4 loads/thread/stage, "memory" asm pins mem-op order):
//  prologue: stage 0,1,2 (12) -> vmcnt(4) retires 0,1 -> A-loads (compiler-
//  waited at cvt use) -> s_barrier -> Bf preload from slab0.
//  iter t: stage t+3 -> in-flight {t+2?,t+3}; bottom vmcnt(4) retires t+2.
//  Rotation reads slab t+1: retired at bottom of t-1 ✓.
// ---------------------------------------------------------------------------
__launch_bounds__(256, 2)
__global__ void pc_gemm1(const float* __restrict__ x, const _Float16* __restrict__ ph,
                         int* __restrict__ out, int* __restrict__ c1,
                         int* __restrict__ l1) {
    __shared__ _Float16 ringmem[32768];   // 64 KB: 4 x 16 KB B slabs
    char* ring = (char*)ringmem;

    const int tid = threadIdx.x;
    const int l = tid & 63;
    const int w = tid >> 6;               // wave 0..3

    const char* phb = (const char*)ph;

    // Prologue: stage slabs 0,1,2 into bufs 0,1,2 (4 loads/thread each).
#pragma unroll
    for (int ss = 0; ss < 3; ++ss) {
        const char* src = phb + ss * 16384 + w * 4096 + (size_t)l * 16;
        char* dst = ring + ss * 16384 + w * 4096;
#pragma unroll
        for (int i = 0; i < 4; ++i)
            __builtin_amdgcn_global_load_lds((const AS1 void*)(src + i * 1024),
                                             (AS3 void*)(dst + i * 1024), 16, 0, 0);
    }
    // Retire slabs 0,1 (slab2 stays in flight). "memory" pins mem-op order.
    asm volatile("s_waitcnt vmcnt(4)" ::: "memory");

    // A-frags: per-lane NT loads from x, fp16-convert in regs (== old phase-1:
    // row = rt*16 + (l&15), k0 = kf*32 + (l>>4)*8, round-to-nearest cast).
    const int wrow = blockIdx.x * 128 + w * 32;
    half8 A[2][8];
#pragma unroll
    for (int rt = 0; rt < 2; ++rt)
#pragma unroll
        for (int kf = 0; kf < 8; ++kf) {
            const f32x4v* sp = (const f32x4v*)(x +
                (size_t)(wrow + rt * 16 + (l & 15)) * 256 + kf * 32 + (l >> 4) * 8);
            f32x4v a = __builtin_nontemporal_load(sp);
            f32x4v b = __builtin_nontemporal_load(sp + 1);
            half8 h;
            h[0] = (_Float16)a[0]; h[1] = (_Float16)a[1];
            h[2] = (_Float16)a[2]; h[3] = (_Float16)a[3];
            h[4] = (_Float16)b[0]; h[5] = (_Float16)b[1];
            h[6] = (_Float16)b[2]; h[7] = (_Float16)b[3];
            A[rt][kf] = h;
        }

    // All 4 waves' slab-0/1 writes visible after this barrier.
    asm volatile("s_barrier" ::: "memory");

    // Preload slab 0's B frags (ct 0,1) into registers.
    const int lofs = l * 16;
    half8 Bf0[8], Bf1[8];
#pragma unroll
    for (int k = 0; k < 8; ++k) {
        Bf0[k] = *(const half8*)(ring + k * 1024 + lofs);
        Bf1[k] = *(const half8*)(ring + 8192 + k * 1024 + lofs);
    }

    // Trackers: 8 per lane (rt*4+reg rows); ic encodes slab*2+ct.
    float t1[8], t2[8];
    int ic[8];
#pragma unroll
    for (int s = 0; s < 8; ++s) { t1[s] = -FLT_MAX; t2[s] = -FLT_MAX; ic[s] = 0; }

    for (int t = 0; t < 64; ++t) {
        // Stage slab (t+3)&63 -> buf[(t+3)&3] (last rotation-read at t-2; all
        // waves crossed t-1's barrier after those reads' lgkm-forced completion).
        {
            int tn = (t + 3) & 63;
            const char* src = phb + (size_t)tn * 16384 + w * 4096 + (size_t)l * 16;
            char* dst = ring + ((t + 3) & 3) * 16384 + w * 4096;
#pragma unroll
            for (int i = 0; i < 4; ++i)
                __builtin_amdgcn_global_load_lds((const AS1 void*)(src + i * 1024),
                                                 (AS3 void*)(dst + i * 1024), 16, 0, 0);
        }

        // Slab t+1 (rotation source) is LDS-resident: retired at bottom of t-1.
        const char* nbp = ring + ((t + 1) & 3) * 16384 + lofs;

        f32x4 a00 = {}, a10 = {}, a01 = {}, a11 = {};
#pragma unroll
        for (int k = 0; k < 8; ++k) {
            a00 = __builtin_amdgcn_mfma_f32_16x16x32_f16(A[0][k], Bf0[k], a00, 0, 0, 0);
            a10 = __builtin_amdgcn_mfma_f32_16x16x32_f16(A[1][k], Bf0[k], a10, 0, 0, 0);
            Bf0[k] = *(const half8*)(nbp + k * 1024);            // refill ct0,k
            a01 = __builtin_amdgcn_mfma_f32_16x16x32_f16(A[0][k], Bf1[k], a01, 0, 0, 0);
            a11 = __builtin_amdgcn_mfma_f32_16x16x32_f16(A[1][k], Bf1[k], a11, 0, 0, 0);
            Bf1[k] = *(const half8*)(nbp + 8192 + k * 1024);     // refill ct1,k
        }

        // Top-2 update; cells ascend (ct0 then ct1) -> ties keep earliest.
#define UPD2(V, TR, CODE)                                                  \
        {                                                                  \
            float v = (V);                                                 \
            float nt2 = __builtin_amdgcn_fmed3f(t1[TR], t2[TR], v);        \
            ic[TR] = (v > t1[TR]) ? (CODE) : ic[TR];                       \
            t1[TR] = fmaxf(t1[TR], v);                                     \
            t2[TR] = nt2;                                                  \
        }
#pragma unroll
        for (int reg = 0; reg < 4; ++reg) {
            UPD2(a00[reg], reg,     t * 2)
            UPD2(a01[reg], reg,     t * 2 + 1)
            UPD2(a10[reg], 4 + reg, t * 2)
            UPD2(a11[reg], 4 + reg, t * 2 + 1)
        }
#undef UPD2

        // Counted wait fused with barrier: retires slab t+2 (rotation source
        // next iter); slab t+3's stage stays in flight across the barrier.
        asm volatile("s_waitcnt vmcnt(4)\n\ts_barrier" ::: "memory");
    }

    // Drain wrap-tail stages (writes to dead buffers) before kernel exit.
    asm volatile("s_waitcnt vmcnt(0)" ::: "memory");

    // Butterfly across the 16 column lanes (masks < 16 keep l>>4 fixed).
    int idx[8];
#pragma unroll
    for (int s = 0; s < 8; ++s) idx[s] = ic[s] * 16 + (l & 15);   // == global cell
#pragma unroll
    for (int m = 1; m <= 8; m <<= 1) {
#pragma unroll
        for (int s = 0; s < 8; ++s) {
            float ot1 = __shfl_xor(t1[s], m, 64);
            int   oi  = __shfl_xor(idx[s], m, 64);
            float ot2 = __shfl_xor(t2[s], m, 64);
            float nt2 = fmaxf(fminf(t1[s], ot1), fmaxf(t2[s], ot2));
            if (ot1 > t1[s] || (ot1 == t1[s] && oi < idx[s])) { t1[s] = ot1; idx[s] = oi; }
            t2[s] = nt2;
        }
    }

    // Epilogue: lanes with (l&15)==0 own row = wrow + rt*16 + (l>>4)*4 + reg.
    // No cross-wave combine needed (wave owns its rows for ALL cells).
#pragma unroll
    for (int s = 0; s < 8; ++s) {
        int rt = s >> 2, reg = s & 3;
        int row = wrow + rt * 16 + (l >> 4) * 4 + reg;
        bool vld = (l & 15) == 0;
        if (vld) out[row] = idx[s];
        bool f = vld && (t1[s] - t2[s] < M1);
        unsigned long long msk = __ballot(f);
        int cnt = __popcll(msk);
        if (cnt) {   // wave-uniform
            int prefix = __popcll(msk & ((1ull << l) - 1ull));
            int bpos = 0;
            if (l == 0) bpos = atomicAdd(c1, cnt);
            bpos = __shfl(bpos, 0, 64);
            if (f) {
                int pos = bpos + prefix;
                if (pos < CAP1) l1[pos] = row;
            }
        }
    }
}

// ---------------------------------------------------------------------------
// Kernel B: fp16x2 3-pass MFMA on flagged rows, barrier-free K-loop.
// Grid-stride over 16-row groups (grid 256). 256 thr = 4 waves (wc = col
// group). Per-sim arithmetic IDENTICAL to rounds 3-4 (verified absmax 0).
// ---------------------------------------------------------------------------
__launch_bounds__(256, 2)
__global__ void pc_rescue2(const float* __restrict__ x, const _Float16* __restrict__ ph,
                           const _Float16* __restrict__ pl,
                           const int* __restrict__ c1, const int* __restrict__ l1,
                           int* __restrict__ out, int* __restrict__ c2,
                           int* __restrict__ l2) {
    const int n0 = *c1;
    const int n = n0 < CAP1 ? n0 : CAP1;
    const int G = (n + 15) >> 4;
    const int tid = threadIdx.x;
    const int l = tid & 63, wc = tid >> 6;

    __shared__ float rT1[64];
    __shared__ int   rI1[64];
    __shared__ float rT2[64];

    for (int g = blockIdx.x; g < G; g += gridDim.x) {
        const int base = g * 16;
        __syncthreads();   // protect shared reuse across group iterations

        const int rslot = base + (l & 15);
        const int my_row = l1[rslot < n ? rslot : (n - 1)];

        half8 Ah[8], Al[8];
#pragma unroll
        for (int kf = 0; kf < 8; ++kf) {
            const float* s = x + (size_t)my_row * 256 + kf * 32 + (l >> 4) * 8;
            float4 a = *(const float4*)s, b = *(const float4*)(s + 4);
            float v[8] = {a.x, a.y, a.z, a.w, b.x, b.y, b.z, b.w};
#pragma unroll
            for (int j = 0; j < 8; ++j) {
                _Float16 hi = (_Float16)v[j];
                Ah[kf][j] = hi;
                Al[kf][j] = (_Float16)((v[j] - (float)hi) * 2048.0f);
            }
        }

        const _Float16* bh = ph + wc * 4096 + (size_t)l * 8;
        const _Float16* bl = pl + wc * 4096 + (size_t)l * 8;
        half8 BH[4], BL[4];
#pragma unroll
        for (int j = 0; j < 4; ++j) {
            BH[j] = *(const half8*)(bh + j * 512);
            BL[j] = *(const half8*)(bl + j * 512);
        }

        float t1[4], t2[4];
        int ic[4];
#pragma unroll
        for (int s = 0; s < 4; ++s) { t1[s] = -FLT_MAX; t2[s] = -FLT_MAX; ic[s] = 0; }

        for (int t = 0; t < 32; ++t) {
            const _Float16* bth = bh + t * 16384;
            const _Float16* btl = bl + t * 16384;
            f32x4 hh = {}, hl = {}, lh = {};
#pragma unroll
            for (int k = 0; k < 8; ++k) {
                half8 Bh_ = BH[k & 3], Bl_ = BL[k & 3];
                int off = (k < 4) ? (k + 4) * 512 : (16384 + (k - 4) * 512);
                BH[k & 3] = *(const half8*)(bth + off);
                BL[k & 3] = *(const half8*)(btl + off);
                hh = __builtin_amdgcn_mfma_f32_16x16x32_f16(Ah[k], Bh_, hh, 0, 0, 0);
                hl = __builtin_amdgcn_mfma_f32_16x16x32_f16(Ah[k], Bl_, hl, 0, 0, 0);
                lh = __builtin_amdgcn_mfma_f32_16x16x32_f16(Al[k], Bh_, lh, 0, 0, 0);
            }
#pragma unroll
            for (int reg = 0; reg < 4; ++reg) {
                float v = hh[reg] + (hl[reg] + lh[reg]) * (1.0f / 2048.0f);
                float nt2 = __builtin_amdgcn_fmed3f(t1[reg], t2[reg], v);
                ic[reg] = (v > t1[reg]) ? t : ic[reg];
                t1[reg] = fmaxf(t1[reg], v);
                t2[reg] = nt2;
            }
        }

        int idx[4];
#pragma unroll
        for (int s = 0; s < 4; ++s) idx[s] = (ic[s] * 4 + wc) * 16 + (l & 15);
#pragma unroll
        for (int m = 1; m <= 8; m <<= 1) {
#pragma unroll
            for (int s = 0; s < 4; ++s) {
                float ot1 = __shfl_xor(t1[s], m, 64);
                int   oi  = __shfl_xor(idx[s], m, 64);
                float ot2 = __shfl_xor(t2[s], m, 64);
                float nt2 = fmaxf(fminf(t1[s], ot1), fmaxf(t2[s], ot2));
                if (ot1 > t1[s] || (ot1 == t1[s] && oi < idx[s])) { t1[s] = ot1; idx[s] = oi; }
                t2[s] = nt2;
            }
        }

        if ((l & 15) == 0) {
#pragma unroll
            for (int reg = 0; reg < 4; ++reg) {
                int r = (l >> 4) * 4 + reg;
                rT1[r * 4 + wc] = t1[reg];
                rI1[r * 4 + wc] = idx[reg];
                rT2[r * 4 + wc] = t2[reg];
            }
        }
        __syncthreads();
        if (tid < 16) {
            float T1 = -FLT_MAX, T2 = -FLT_MAX; int I1 = 0x7FFFFFFF;
#pragma unroll
            for (int q = 0; q < 4; ++q) {
                float v1 = rT1[tid * 4 + q];
                int   vi = rI1[tid * 4 + q];
                float v2 = rT2[tid * 4 + q];
                float nt2 = fmaxf(fminf(T1, v1), fmaxf(T2, v2));
                if (v1 > T1 || (v1 == T1 && vi < I1)) { T1 = v1; I1 = vi; }
                T2 = nt2;
            }
            int slot = base + tid;
            if (slot < n) {
                int grow = l1[slot];
                out[grow] = I1;
                if (T1 - T2 < M2) {
                    int pos = atomicAdd(c2, 1);
                    if (pos < CAP2) l2[pos] = grow;
                }
            }
        }
    }
}

// ---------------------------------------------------------------------------
// Kernel C: exact fp32 argmax for residual rows (expected ~30).
// UNCHANGED arithmetic from rounds 2-4 (matches numpy on this dataset).
// ---------------------------------------------------------------------------
__global__ void rescue3(const float* __restrict__ x, const float* __restrict__ p,
                        const int* __restrict__ count, const int* __restrict__ list,
                        int* __restrict__ out) {
    __shared__ float xrow[256];
    __shared__ float pch[32][260];
    __shared__ float red2[32][9];
    __shared__ float bvs[32];
    __shared__ int   bis[32];
    const int tid = threadIdx.x;
    const int n0 = *count;
    const int n = n0 < CAP2 ? n0 : CAP2;
    for (int e = blockIdx.x; e < n; e += gridDim.x) {
        const int row = list[e];
        __syncthreads();
        if (tid < 64) {
            float4 v = *(const float4*)(x + (size_t)row * 256 + tid * 4);
            *(float4*)(&xrow[tid * 4]) = v;
        }
        float bv = -FLT_MAX; int bi = 0;
        const int cell = tid & 31, kq = tid >> 5;
        for (int c0 = 0; c0 < NUM_CELLS; c0 += 32) {
            __syncthreads();
#pragma unroll
            for (int i = 0; i < 8; ++i) {
                int f = tid + i * 256;
                int cr = f >> 6, k4 = (f & 63) * 4;
                float4 v = *(const float4*)(p + (size_t)(c0 + cr) * 256 + k4);
                *(float4*)(&pch[cr][k4]) = v;
            }
            __syncthreads();
            float s = 0.f;
#pragma unroll
            for (int j = 0; j < 8; ++j) {
                float4 pv = *(const float4*)(&pch[cell][kq * 32 + j * 4]);
                float4 xv = *(const float4*)(&xrow[kq * 32 + j * 4]);
                s = fmaf(xv.x, pv.x, s); s = fmaf(xv.y, pv.y, s);
                s = fmaf(xv.z, pv.z, s); s = fmaf(xv.w, pv.w, s);
            }
            red2[cell][kq] = s;
            __syncthreads();
            if (tid < 32) {
                float dot = 0.f;
#pragma unroll
                for (int q = 0; q < 8; ++q) dot += red2[tid][q];
                if (dot > bv) { bv = dot; bi = c0 + tid; }
            }
        }
        if (tid < 32) { bvs[tid] = bv; bis[tid] = bi; }
        __syncthreads();
        if (tid == 0) {
            float B = bvs[0]; int BI = bis[0];
#pragma unroll
            for (int t = 1; t < 32; ++t)
                if (bvs[t] > B || (bvs[t] == B && bis[t] < BI)) { B = bvs[t]; BI = bis[t]; }
            out[row] = BI;
        }
    }
}

// ---------------------------------------------------------------------------
// Fallback (round-1 fp32 vector path) if ws too small.
// ---------------------------------------------------------------------------
#define BM 64
#define BN 64
#define BK 32
#define XP 260
#define PP 68
__launch_bounds__(256, 2)
__global__ void placecells_argmax_fp32(const float* __restrict__ x,
                                       const float* __restrict__ pc,
                                       int* __restrict__ out) {
    __shared__ float xs[BM * XP];
    __shared__ float ps[BK * PP];
    const int tid = threadIdx.x;
    const int tx = tid & 15;
    const int ty = tid >> 4;
    const float* xg = x + (size_t)blockIdx.x * (BM * CELL_DIM);
#pragma unroll
    for (int i = 0; i < 16; ++i) {
        int f = tid + i * 256;
        int s = f >> 6, k4 = (f & 63) << 2;
        *(float4*)(&xs[s * XP + k4]) = *(const float4*)(xg + s * CELL_DIM + k4);
    }
    __syncthreads();
    float runv[4]; int runi[4];
#pragma unroll
    for (int si = 0; si < 4; ++si) { runv[si] = -FLT_MAX; runi[si] = 0; }
    for (int jc = 0; jc < NUM_CELLS; jc += BN) {
        float acc[4][4];
#pragma unroll
        for (int si = 0; si < 4; ++si)
#pragma unroll
            for (int cj = 0; cj < 4; ++cj) acc[si][cj] = 0.0f;
        for (int kc = 0; kc < CELL_DIM; kc += BK) {
            __syncthreads();
#pragma unroll
            for (int i = 0; i < 2; ++i) {
                int f = tid + i * 256;
                int c = f >> 3, k4 = (f & 7) << 2;
                float4 v = *(const float4*)(pc + (size_t)(jc + c) * CELL_DIM + kc + k4);
                ps[(k4 + 0) * PP + c] = v.x; ps[(k4 + 1) * PP + c] = v.y;
                ps[(k4 + 2) * PP + c] = v.z; ps[(k4 + 3) * PP + c] = v.w;
            }
            __syncthreads();
#pragma unroll
            for (int kk = 0; kk < BK; kk += 4) {
                float4 xv[4];
#pragma unroll
                for (int si = 0; si < 4; ++si)
                    xv[si] = *(const float4*)(&xs[(ty * 4 + si) * XP + kc + kk]);
#pragma unroll
                for (int kt = 0; kt < 4; ++kt) {
                    float4 pv = *(const float4*)(&ps[(kk + kt) * PP + tx * 4]);
#pragma unroll
                    for (int si = 0; si < 4; ++si) {
                        float xk = (kt == 0) ? xv[si].x : (kt == 1) ? xv[si].y :
                                   (kt == 2) ? xv[si].z : xv[si].w;
                        acc[si][0] = fmaf(xk, pv.x, acc[si][0]);
                        acc[si][1] = fmaf(xk, pv.y, acc[si][1]);
                        acc[si][2] = fmaf(xk, pv.z, acc[si][2]);
                        acc[si][3] = fmaf(xk, pv.w, acc[si][3]);
                    }
                }
            }
        }
#pragma unroll
        for (int si = 0; si < 4; ++si)
#pragma unroll
            for (int cj = 0; cj < 4; ++cj) {
                int idx = jc + tx * 4 + cj;
                if (acc[si][cj] > runv[si]) { runv[si] = acc[si][cj]; runi[si] = idx; }
            }
    }
    __syncthreads();
    float* rv = ps; int* ri = (int*)(ps + 1024);
#pragma unroll
    for (int si = 0; si < 4; ++si) {
        int s = ty * 4 + si;
        rv[s * 16 + tx] = runv[si]; ri[s * 16 + tx] = runi[si];
    }
    __syncthreads();
    if (tid < BM) {
        float bv = rv[tid * 16]; int bi = ri[tid * 16];
#pragma unroll
        for (int t = 1; t < 16; ++t) {
            float v = rv[tid * 16 + t]; int i = ri[tid * 16 + t];
            if (v > bv || (v == bv && i < bi)) { bv = v; bi = i; }
        }
        out[(size_t)blockIdx.x * BM + tid] = bi;
    }
}

extern "C" void kernel_launch(void* const* d_in, const int* in_sizes, int n_in,
                              void* d_out, int out_size, void* d_ws, size_t ws_size,
                              hipStream_t stream) {
    const float* x  = (const float*)d_in[0];   // (131072, 256) fp32
    const float* pc = (const float*)d_in[1];   // (2048, 256) fp32
    int* out = (int*)d_out;

    if (ws_size >= (size_t)WS_NEEDED) {
        char* ws = (char*)d_ws;
        int* c1 = (int*)(ws + WS_C1);
        int* c2 = (int*)(ws + WS_C2);
        int* l1 = (int*)(ws + WS_L1);
        int* l2 = (int*)(ws + WS_L2);
        _Float16* ph = (_Float16*)(ws + WS_PH);
        _Float16* pl = (_Float16*)(ws + WS_PL);
        prep_p<<<256, 256, 0, stream>>>(pc, ph, pl, c1, c2);
        pc_gemm1<<<N_STATES / 128, 256, 0, stream>>>(x, ph, out, c1, l1);
        pc_rescue2<<<256, 256, 0, stream>>>(x, ph, pl, c1, l1, out, c2, l2);
        rescue3<<<64, 256, 0, stream>>>(x, pc, c2, l2, out);
    } else {
        placecells_argmax_fp32<<<N_STATES / BM, 256, 0, stream>>>(x, pc, out);
    }
}

// Round 7
// 434.553 us; speedup vs baseline: 1.1155x; 1.0221x over previous
//
#include <hip/hip_runtime.h>
#include <float.h>
#include <stdint.h>

#define NUM_CELLS 2048
#define CELL_DIM  256
#define N_STATES  131072

typedef _Float16 half8 __attribute__((ext_vector_type(8)));
typedef float    f32x4 __attribute__((ext_vector_type(4)));
typedef float    f32x4v __attribute__((ext_vector_type(4)));   // nt-load-able

// Stage-1 (1-pass fp16) sim-difference noise sigma ~6e-3; M1 ~ 17 sigma.
#define M1 0.10f
// Stage-2 (fp16x2 3-pass) noise sigma ~1.5e-5; M2 = 0.0008 ~ 50 sigma.
#define M2 0.0008f
#define CAP1 32768
#define CAP2 4096

// ws layout (bytes). ws_size >= WS_NEEDED confirmed (rounds 2-4 ran this path).
#define WS_C1 0
#define WS_C2 4
#define WS_L1 1024
#define WS_L2 (WS_L1 + 4 * CAP1)                    // 132096
#define WS_PH 262144
#define WS_PL (WS_PH + 1048576)
// 128 KB slack after pl retained (layout unchanged from verified rounds).
#define WS_NEEDED (WS_PL + 1048576 + 131072)        // 2490368

#define AS1 __attribute__((address_space(1)))
#define AS3 __attribute__((address_space(3)))

// ---------------------------------------------------------------------------
// Prep: p fp32 -> B-fragment-order fp16 hi + (lo*2048) arrays; zero counters.
// Frag order (16x16x32 f16 B): half8 index d = (ct*8 + kf)*64 + l, where
// cell = ct*16 + (l&15), k = kf*32 + (l>>4)*8 + j.
// ---------------------------------------------------------------------------
__global__ void prep_p(const float* __restrict__ p, _Float16* __restrict__ ph,
                       _Float16* __restrict__ pl, int* __restrict__ c1,
                       int* __restrict__ c2) {
    int d = blockIdx.x * 256 + threadIdx.x;   // 65536 dests
    if (d == 0) { *c1 = 0; *c2 = 0; }
    int l = d & 63, kf = (d >> 6) & 7, ct = d >> 9;
    int cell = ct * 16 + (l & 15);
    int k0 = kf * 32 + (l >> 4) * 8;
    const float* s = p + cell * 256 + k0;
    float4 a = *(const float4*)s, b = *(const float4*)(s + 4);
    float v[8] = {a.x, a.y, a.z, a.w, b.x, b.y, b.z, b.w};
    half8 h, lo;
#pragma unroll
    for (int j = 0; j < 8; ++j) {
        _Float16 hi = (_Float16)v[j];
        h[j] = hi;
        lo[j] = (_Float16)((v[j] - (float)hi) * 2048.0f);  // scaled: no fp16 denorms
    }
    *(half8*)(ph + (size_t)d * 8) = h;
    *(half8*)(pl + (size_t)d * 8) = lo;
}

// ---------------------------------------------------------------------------
// Kernel A (R7): 1-pass fp16 MFMA GEMM, 4-wave blocks, 3 blocks/CU target.
// R6 FAILED (absmax 1344): its mid-iter "vmcnt(4)" had NO barrier, but the
// ct1-burst refills read slab t+1 quarters staged by OTHER waves -- vmcnt is
// per-wave, so wave 2 could read before wave 0's global_load_lds landed.
// R7 fix: ONE fused "s_waitcnt vmcnt(4); s_barrier" per iteration, placed
// MID-iteration (between ct0 and ct1 bursts); bottom barrier dropped.
// Seal ledger (4 loads/thread/stage; stage idx wraps &63 so count uniform):
//  top of t: issue stage(t+2) -> outstanding {t+1, t+2} = 8.
//  ct0 burst: refills read slab t ct1 (p0+8K) -- sealed at mid-(t-1)
//    (each wave's vmcnt retired ITS stage(t) there, then barrier). ✓
//  mid-t fused wait: vmcnt(4) retires stage(t+1) in EVERY wave, then
//    s_barrier -> slab t+1 sealed for all. ✓
//  ct1 burst: refills read slab t+1 ct0 (p1) -- sealed ✓.
//  Reuse: stage at top of t writes slab t-1's buffer; its last reads were
//    iter t-1's ct0 refills, before the mid-(t-1) barrier. ✓
//  Prologue: stage 0,1; A-loads (their converts drain earlier-issued stage
//    loads -- conservative); fused vmcnt(4)+barrier seals slabs 0,1; preload
//    Bf from slab 0 ct0. Tail (t>=62) stages wrap copies into buffers whose
//    subsequent reads are discarded (mapped, harmless); final vmcnt(0).
// Structure (from R5/R6): wave owns 32 rows for ALL cells (no cross-wave
// reduce); A per-lane NT-loaded + converted in regs (bit-identical to the
// verified staging path); LDS = 3 x 16 KB ring = 48 KB -> 3 blocks/CU;
// single shared Bf[8] set (32 regs) with in-place rotation: ct0-burst
// refills from slab t's ct1 (p0+8K), ct1-burst refills from slab t+1's ct0
// (p1). ~150 regs -> __launch_bounds__(256,3) without spill.
// Arithmetic bit-identical to R5 (same A loads/casts, same ph bytes, each
// acc chain k-ascending, tracker update ct0-then-ct1 per ascending slab).
// ---------------------------------------------------------------------------
__launch_bounds__(256, 3)
__global__ void pc_gemm1(const float* __restrict__ x, const _Float16* __restrict__ ph,
                         int* __restrict__ out, int* __restrict__ c1,
                         int* __restrict__ l1) {
    __shared__ _Float16 ringmem[24576];   // 48 KB: 3 x 16 KB B slabs
    char* ring = (char*)ringmem;

    const int tid = threadIdx.x;
    const int l = tid & 63;
    const int w = tid >> 6;               // wave 0..3

    const char* phb = (const char*)ph;

    // Prologue: stage slabs 0,1 into bufs 0,1 (4 loads/thread each).
#pragma unroll
    for (int ss = 0; ss < 2; ++ss) {
        const char* src = phb + ss * 16384 + w * 4096 + (size_t)l * 16;
        char* dst = ring + ss * 16384 + w * 4096;
#pragma unroll
        for (int i = 0; i < 4; ++i)
            __builtin_amdgcn_global_load_lds((const AS1 void*)(src + i * 1024),
                                             (AS3 void*)(dst + i * 1024), 16, 0, 0);
    }

    // A-frags: per-lane NT loads from x, fp16-convert in regs (same addresses
    // + rounding as verified rounds: row = rt*16+(l&15), k0 = kf*32+(l>>4)*8).
    const int wrow = blockIdx.x * 128 + w * 32;
    half8 A[2][8];
#pragma unroll
    for (int rt = 0; rt < 2; ++rt)
#pragma unroll
        for (int kf = 0; kf < 8; ++kf) {
            const f32x4v* sp = (const f32x4v*)(x +
                (size_t)(wrow + rt * 16 + (l & 15)) * 256 + kf * 32 + (l >> 4) * 8);
            f32x4v a = __builtin_nontemporal_load(sp);
            f32x4v b = __builtin_nontemporal_load(sp + 1);
            half8 h;
            h[0] = (_Float16)a[0]; h[1] = (_Float16)a[1];
            h[2] = (_Float16)a[2]; h[3] = (_Float16)a[3];
            h[4] = (_Float16)b[0]; h[5] = (_Float16)b[1];
            h[6] = (_Float16)b[2]; h[7] = (_Float16)b[3];
            A[rt][kf] = h;
        }

    // Fused wait+barrier: all stage-0/1 writes retired (A-converts already
    // drained them -- conservative) and sealed for all waves.
    asm volatile("s_waitcnt vmcnt(4)\n\ts_barrier" ::: "memory");

    // Preload slab 0's ct0 frags into the single Bf set.
    const int lofs = l * 16;
    half8 Bf[8];
#pragma unroll
    for (int k = 0; k < 8; ++k)
        Bf[k] = *(const half8*)(ring + k * 1024 + lofs);

    // Rotating buffer pointers: p0 = slab t, p1 = slab t+1, p2 = stage dest.
    char* p0 = ring;
    char* p1 = ring + 16384;
    char* p2 = ring + 32768;

    // Trackers: 8 per lane (rt*4+reg rows); ic encodes slab*2+ct.
    float t1[8], t2[8];
    int ic[8];
#pragma unroll
    for (int s = 0; s < 8; ++s) { t1[s] = -FLT_MAX; t2[s] = -FLT_MAX; ic[s] = 0; }

#define UPD2(V, TR, CODE)                                                  \
    {                                                                      \
        float v = (V);                                                     \
        float nt2 = __builtin_amdgcn_fmed3f(t1[TR], t2[TR], v);            \
        ic[TR] = (v > t1[TR]) ? (CODE) : ic[TR];                           \
        t1[TR] = fmaxf(t1[TR], v);                                         \
        t2[TR] = nt2;                                                      \
    }

    for (int t = 0; t < 64; ++t) {
        // Stage slab (t+2)&63 -> p2 (slab t-1's buffer; its last reads were
        // iter t-1's ct0 refills, before the mid-(t-1) barrier).
        {
            int tn = (t + 2) & 63;
            const char* src = phb + (size_t)tn * 16384 + w * 4096 + (size_t)l * 16;
#pragma unroll
            for (int i = 0; i < 4; ++i)
                __builtin_amdgcn_global_load_lds((const AS1 void*)(src + i * 1024),
                                                 (AS3 void*)(p2 + w * 4096 + i * 1024),
                                                 16, 0, 0);
        }

        // ct0 burst: 2 chains x 8; refill Bf[k] <- slab t's ct1 frag k
        // (p0+8K, sealed at mid-(t-1)) right after its last use this slab.
        f32x4 a00 = {}, a10 = {};
#pragma unroll
        for (int k = 0; k < 8; ++k) {
            a00 = __builtin_amdgcn_mfma_f32_16x16x32_f16(A[0][k], Bf[k], a00, 0, 0, 0);
            a10 = __builtin_amdgcn_mfma_f32_16x16x32_f16(A[1][k], Bf[k], a10, 0, 0, 0);
            Bf[k] = *(const half8*)(p0 + 8192 + k * 1024 + lofs);
        }
#pragma unroll
        for (int reg = 0; reg < 4; ++reg) {
            UPD2(a00[reg], reg,     t * 2)
            UPD2(a10[reg], 4 + reg, t * 2)
        }

        // THE seal point (one per iteration): every wave retires ITS
        // stage(t+1) loads (outstanding {t+1,t+2}=8 -> vmcnt(4)), then the
        // barrier makes slab t+1 visible to ALL waves. Stage(t+2) rides
        // across the barrier (never vmcnt(0) in-loop).
        asm volatile("s_waitcnt vmcnt(4)\n\ts_barrier" ::: "memory");

        // ct1 burst: refill Bf[k] <- slab t+1's ct0 frag k (p1, just sealed).
        f32x4 a01 = {}, a11 = {};
#pragma unroll
        for (int k = 0; k < 8; ++k) {
            a01 = __builtin_amdgcn_mfma_f32_16x16x32_f16(A[0][k], Bf[k], a01, 0, 0, 0);
            a11 = __builtin_amdgcn_mfma_f32_16x16x32_f16(A[1][k], Bf[k], a11, 0, 0, 0);
            Bf[k] = *(const half8*)(p1 + k * 1024 + lofs);
        }
#pragma unroll
        for (int reg = 0; reg < 4; ++reg) {
            UPD2(a01[reg], reg,     t * 2 + 1)
            UPD2(a11[reg], 4 + reg, t * 2 + 1)
        }

        // Rotate ring pointers (no bottom barrier: reuse is sealed mid-iter).
        char* tp = p0; p0 = p1; p1 = p2; p2 = tp;
    }
#undef UPD2

    // Drain wrap-tail stages (writes to dead buffers) before LDS dealloc.
    asm volatile("s_waitcnt vmcnt(0)" ::: "memory");

    // Butterfly across the 16 column lanes (masks < 16 keep l>>4 fixed).
    int idx[8];
#pragma unroll
    for (int s = 0; s < 8; ++s) idx[s] = ic[s] * 16 + (l & 15);   // == global cell
#pragma unroll
    for (int m = 1; m <= 8; m <<= 1) {
#pragma unroll
        for (int s = 0; s < 8; ++s) {
            float ot1 = __shfl_xor(t1[s], m, 64);
            int   oi  = __shfl_xor(idx[s], m, 64);
            float ot2 = __shfl_xor(t2[s], m, 64);
            float nt2 = fmaxf(fminf(t1[s], ot1), fmaxf(t2[s], ot2));
            if (ot1 > t1[s] || (ot1 == t1[s] && oi < idx[s])) { t1[s] = ot1; idx[s] = oi; }
            t2[s] = nt2;
        }
    }

    // Epilogue: lanes with (l&15)==0 own row = wrow + rt*16 + (l>>4)*4 + reg.
    // No cross-wave combine needed (wave owns its rows for ALL cells).
#pragma unroll
    for (int s = 0; s < 8; ++s) {
        int rt = s >> 2, reg = s & 3;
        int row = wrow + rt * 16 + (l >> 4) * 4 + reg;
        bool vld = (l & 15) == 0;
        if (vld) out[row] = idx[s];
        bool f = vld && (t1[s] - t2[s] < M1);
        unsigned long long msk = __ballot(f);
        int cnt = __popcll(msk);
        if (cnt) {   // wave-uniform
            int prefix = __popcll(msk & ((1ull << l) - 1ull));
            int bpos = 0;
            if (l == 0) bpos = atomicAdd(c1, cnt);
            bpos = __shfl(bpos, 0, 64);
            if (f) {
                int pos = bpos + prefix;
                if (pos < CAP1) l1[pos] = row;
            }
        }
    }
}

// ---------------------------------------------------------------------------
// Kernel B: fp16x2 3-pass MFMA on flagged rows, barrier-free K-loop.
// Grid-stride over 16-row groups (grid 256). 256 thr = 4 waves (wc = col
// group). Per-sim arithmetic IDENTICAL to rounds 3-4 (verified absmax 0).
// ---------------------------------------------------------------------------
__launch_bounds__(256, 2)
__global__ void pc_rescue2(const float* __restrict__ x, const _Float16* __restrict__ ph,
                           const _Float16* __restrict__ pl,
                           const int* __restrict__ c1, const int* __restrict__ l1,
                           int* __restrict__ out, int* __restrict__ c2,
                           int* __restrict__ l2) {
    const int n0 = *c1;
    const int n = n0 < CAP1 ? n0 : CAP1;
    const int G = (n + 15) >> 4;
    const int tid = threadIdx.x;
    const int l = tid & 63, wc = tid >> 6;

    __shared__ float rT1[64];
    __shared__ int   rI1[64];
    __shared__ float rT2[64];

    for (int g = blockIdx.x; g < G; g += gridDim.x) {
        const int base = g * 16;
        __syncthreads();   // protect shared reuse across group iterations

        const int rslot = base + (l & 15);
        const int my_row = l1[rslot < n ? rslot : (n - 1)];

        half8 Ah[8], Al[8];
#pragma unroll
        for (int kf = 0; kf < 8; ++kf) {
            const float* s = x + (size_t)my_row * 256 + kf * 32 + (l >> 4) * 8;
            float4 a = *(const float4*)s, b = *(const float4*)(s + 4);
            float v[8] = {a.x, a.y, a.z, a.w, b.x, b.y, b.z, b.w};
#pragma unroll
            for (int j = 0; j < 8; ++j) {
                _Float16 hi = (_Float16)v[j];
                Ah[kf][j] = hi;
                Al[kf][j] = (_Float16)((v[j] - (float)hi) * 2048.0f);
            }
        }

        const _Float16* bh = ph + wc * 4096 + (size_t)l * 8;
        const _Float16* bl = pl + wc * 4096 + (size_t)l * 8;
        half8 BH[4], BL[4];
#pragma unroll
        for (int j = 0; j < 4; ++j) {
            BH[j] = *(const half8*)(bh + j * 512);
            BL[j] = *(const half8*)(bl + j * 512);
        }

        float t1[4], t2[4];
        int ic[4];
#pragma unroll
        for (int s = 0; s < 4; ++s) { t1[s] = -FLT_MAX; t2[s] = -FLT_MAX; ic[s] = 0; }

        for (int t = 0; t < 32; ++t) {
            const _Float16* bth = bh + t * 16384;
            const _Float16* btl = bl + t * 16384;
            f32x4 hh = {}, hl = {}, lh = {};
#pragma unroll
            for (int k = 0; k < 8; ++k) {
                half8 Bh_ = BH[k & 3], Bl_ = BL[k & 3];
                int off = (k < 4) ? (k + 4) * 512 : (16384 + (k - 4) * 512);
                BH[k & 3] = *(const half8*)(bth + off);
                BL[k & 3] = *(const half8*)(btl + off);
                hh = __builtin_amdgcn_mfma_f32_16x16x32_f16(Ah[k], Bh_, hh, 0, 0, 0);
                hl = __builtin_amdgcn_mfma_f32_16x16x32_f16(Ah[k], Bl_, hl, 0, 0, 0);
                lh = __builtin_amdgcn_mfma_f32_16x16x32_f16(Al[k], Bh_, lh, 0, 0, 0);
            }
#pragma unroll
            for (int reg = 0; reg < 4; ++reg) {
                float v = hh[reg] + (hl[reg] + lh[reg]) * (1.0f / 2048.0f);
                float nt2 = __builtin_amdgcn_fmed3f(t1[reg], t2[reg], v);
                ic[reg] = (v > t1[reg]) ? t : ic[reg];
                t1[reg] = fmaxf(t1[reg], v);
                t2[reg] = nt2;
            }
        }

        int idx[4];
#pragma unroll
        for (int s = 0; s < 4; ++s) idx[s] = (ic[s] * 4 + wc) * 16 + (l & 15);
#pragma unroll
        for (int m = 1; m <= 8; m <<= 1) {
#pragma unroll
            for (int s = 0; s < 4; ++s) {
                float ot1 = __shfl_xor(t1[s], m, 64);
                int   oi  = __shfl_xor(idx[s], m, 64);
                float ot2 = __shfl_xor(t2[s], m, 64);
                float nt2 = fmaxf(fminf(t1[s], ot1), fmaxf(t2[s], ot2));
                if (ot1 > t1[s] || (ot1 == t1[s] && oi < idx[s])) { t1[s] = ot1; idx[s] = oi; }
                t2[s] = nt2;
            }
        }

        if ((l & 15) == 0) {
#pragma unroll
            for (int reg = 0; reg < 4; ++reg) {
                int r = (l >> 4) * 4 + reg;
                rT1[r * 4 + wc] = t1[reg];
                rI1[r * 4 + wc] = idx[reg];
                rT2[r * 4 + wc] = t2[reg];
            }
        }
        __syncthreads();
        if (tid < 16) {
            float T1 = -FLT_MAX, T2 = -FLT_MAX; int I1 = 0x7FFFFFFF;
#pragma unroll
            for (int q = 0; q < 4; ++q) {
                float v1 = rT1[tid * 4 + q];
                int   vi = rI1[tid * 4 + q];
                float v2 = rT2[tid * 4 + q];
                float nt2 = fmaxf(fminf(T1, v1), fmaxf(T2, v2));
                if (v1 > T1 || (v1 == T1 && vi < I1)) { T1 = v1; I1 = vi; }
                T2 = nt2;
            }
            int slot = base + tid;
            if (slot < n) {
                int grow = l1[slot];
                out[grow] = I1;
                if (T1 - T2 < M2) {
                    int pos = atomicAdd(c2, 1);
                    if (pos < CAP2) l2[pos] = grow;
                }
            }
        }
    }
}

// ---------------------------------------------------------------------------
// Kernel C: exact fp32 argmax for residual rows (expected ~30).
// UNCHANGED arithmetic from rounds 2-4 (matches numpy on this dataset).
// ---------------------------------------------------------------------------
__global__ void rescue3(const float* __restrict__ x, const float* __restrict__ p,
                        const int* __restrict__ count, const int* __restrict__ list,
                        int* __restrict__ out) {
    __shared__ float xrow[256];
    __shared__ float pch[32][260];
    __shared__ float red2[32][9];
    __shared__ float bvs[32];
    __shared__ int   bis[32];
    const int tid = threadIdx.x;
    const int n0 = *count;
    const int n = n0 < CAP2 ? n0 : CAP2;
    for (int e = blockIdx.x; e < n; e += gridDim.x) {
        const int row = list[e];
        __syncthreads();
        if (tid < 64) {
            float4 v = *(const float4*)(x + (size_t)row * 256 + tid * 4);
            *(float4*)(&xrow[tid * 4]) = v;
        }
        float bv = -FLT_MAX; int bi = 0;
        const int cell = tid & 31, kq = tid >> 5;
        for (int c0 = 0; c0 < NUM_CELLS; c0 += 32) {
            __syncthreads();
#pragma unroll
            for (int i = 0; i < 8; ++i) {
                int f = tid + i * 256;
                int cr = f >> 6, k4 = (f & 63) * 4;
                float4 v = *(const float4*)(p + (size_t)(c0 + cr) * 256 + k4);
                *(float4*)(&pch[cr][k4]) = v;
            }
            __syncthreads();
            float s = 0.f;
#pragma unroll
            for (int j = 0; j < 8; ++j) {
                float4 pv = *(const float4*)(&pch[cell][kq * 32 + j * 4]);
                float4 xv = *(const float4*)(&xrow[kq * 32 + j * 4]);
                s = fmaf(xv.x, pv.x, s); s = fmaf(xv.y, pv.y, s);
                s = fmaf(xv.z, pv.z, s); s = fmaf(xv.w, pv.w, s);
            }
            red2[cell][kq] = s;
            __syncthreads();
            if (tid < 32) {
                float dot = 0.f;
#pragma unroll
                for (int q = 0; q < 8; ++q) dot += red2[tid][q];
                if (dot > bv) { bv = dot; bi = c0 + tid; }
            }
        }
        if (tid < 32) { bvs[tid] = bv; bis[tid] = bi; }
        __syncthreads();
        if (tid == 0) {
            float B = bvs[0]; int BI = bis[0];
#pragma unroll
            for (int t = 1; t < 32; ++t)
                if (bvs[t] > B || (bvs[t] == B && bis[t] < BI)) { B = bvs[t]; BI = bis[t]; }
            out[row] = BI;
        }
    }
}

// ---------------------------------------------------------------------------
// Fallback (round-1 fp32 vector path) if ws too small.
// ---------------------------------------------------------------------------
#define BM 64
#define BN 64
#define BK 32
#define XP 260
#define PP 68
__launch_bounds__(256, 2)
__global__ void placecells_argmax_fp32(const float* __restrict__ x,
                                       const float* __restrict__ pc,
                                       int* __restrict__ out) {
    __shared__ float xs[BM * XP];
    __shared__ float ps[BK * PP];
    const int tid = threadIdx.x;
    const int tx = tid & 15;
    const int ty = tid >> 4;
    const float* xg = x + (size_t)blockIdx.x * (BM * CELL_DIM);
#pragma unroll
    for (int i = 0; i < 16; ++i) {
        int f = tid + i * 256;
        int s = f >> 6, k4 = (f & 63) << 2;
        *(float4*)(&xs[s * XP + k4]) = *(const float4*)(xg + s * CELL_DIM + k4);
    }
    __syncthreads();
    float runv[4]; int runi[4];
#pragma unroll
    for (int si = 0; si < 4; ++si) { runv[si] = -FLT_MAX; runi[si] = 0; }
    for (int jc = 0; jc < NUM_CELLS; jc += BN) {
        float acc[4][4];
#pragma unroll
        for (int si = 0; si < 4; ++si)
#pragma unroll
            for (int cj = 0; cj < 4; ++cj) acc[si][cj] = 0.0f;
        for (int kc = 0; kc < CELL_DIM; kc += BK) {
            __syncthreads();
#pragma unroll
            for (int i = 0; i < 2; ++i) {
                int f = tid + i * 256;
                int c = f >> 3, k4 = (f & 7) << 2;
                float4 v = *(const float4*)(pc + (size_t)(jc + c) * CELL_DIM + kc + k4);
                ps[(k4 + 0) * PP + c] = v.x; ps[(k4 + 1) * PP + c] = v.y;
                ps[(k4 + 2) * PP + c] = v.z; ps[(k4 + 3) * PP + c] = v.w;
            }
            __syncthreads();
#pragma unroll
            for (int kk = 0; kk < BK; kk += 4) {
                float4 xv[4];
#pragma unroll
                for (int si = 0; si < 4; ++si)
                    xv[si] = *(const float4*)(&xs[(ty * 4 + si) * XP + kc + kk]);
#pragma unroll
                for (int kt = 0; kt < 4; ++kt) {
                    float4 pv = *(const float4*)(&ps[(kk + kt) * PP + tx * 4]);
#pragma unroll
                    for (int si = 0; si < 4; ++si) {
                        float xk = (kt == 0) ? xv[si].x : (kt == 1) ? xv[si].y :
                                   (kt == 2) ? xv[si].z : xv[si].w;
                        acc[si][0] = fmaf(xk, pv.x, acc[si][0]);
                        acc[si][1] = fmaf(xk, pv.y, acc[si][1]);
                        acc[si][2] = fmaf(xk, pv.z, acc[si][2]);
                        acc[si][3] = fmaf(xk, pv.w, acc[si][3]);
                    }
                }
            }
        }
#pragma unroll
        for (int si = 0; si < 4; ++si)
#pragma unroll
            for (int cj = 0; cj < 4; ++cj) {
                int idx = jc + tx * 4 + cj;
                if (acc[si][cj] > runv[si]) { runv[si] = acc[si][cj]; runi[si] = idx; }
            }
    }
    __syncthreads();
    float* rv = ps; int* ri = (int*)(ps + 1024);
#pragma unroll
    for (int si = 0; si < 4; ++si) {
        int s = ty * 4 + si;
        rv[s * 16 + tx] = runv[si]; ri[s * 16 + tx] = runi[si];
    }
    __syncthreads();
    if (tid < BM) {
        float bv = rv[tid * 16]; int bi = ri[tid * 16];
#pragma unroll
        for (int t = 1; t < 16; ++t) {
            float v = rv[tid * 16 + t]; int i = ri[tid * 16 + t];
            if (v > bv || (v == bv && i < bi)) { bv = v; bi = i; }
        }
        out[(size_t)blockIdx.x * BM + tid] = bi;
    }
}

extern "C" void kernel_launch(void* const* d_in, const int* in_sizes, int n_in,
                              void* d_out, int out_size, void* d_ws, size_t ws_size,
                              hipStream_t stream) {
    const float* x  = (const float*)d_in[0];   // (131072, 256) fp32
    const float* pc = (const float*)d_in[1];   // (2048, 256) fp32
    int* out = (int*)d_out;

    if (ws_size >= (size_t)WS_NEEDED) {
        char* ws = (char*)d_ws;
        int* c1 = (int*)(ws + WS_C1);
        int* c2 = (int*)(ws + WS_C2);
        int* l1 = (int*)(ws + WS_L1);
        int* l2 = (int*)(ws + WS_L2);
        _Float16* ph = (_Float16*)(ws + WS_PH);
        _Float16* pl = (_Float16*)(ws + WS_PL);
        prep_p<<<256, 256, 0, stream>>>(pc, ph, pl, c1, c2);
        pc_gemm1<<<N_STATES / 128, 256, 0, stream>>>(x, ph, out, c1, l1);
        pc_rescue2<<<256, 256, 0, stream>>>(x, ph, pl, c1, l1, out, c2, l2);
        rescue3<<<64, 256, 0, stream>>>(x, pc, c2, l2, out);
    } else {
        placecells_argmax_fp32<<<N_STATES / BM, 256, 0, stream>>>(x, pc, out);
    }
}